// Round 1
// baseline (513.187 us; speedup 1.0000x reference)
//
#include <hip/hip_runtime.h>
#include <math.h>

#define N_NODES 50000
#define F_IN 256
#define HID 128
#define C_OUT 40

// ---------------- degree / dinv ----------------
__global__ void k_deg(const int* __restrict__ dst, int E, int* __restrict__ counts) {
    int e = blockIdx.x * 256 + threadIdx.x;
    if (e < E) atomicAdd(&counts[dst[e]], 1);
}

__global__ void k_dinv(const int* __restrict__ counts, float* __restrict__ dinv, int N) {
    int i = blockIdx.x * 256 + threadIdx.x;
    if (i < N) dinv[i] = rsqrtf((float)(counts[i] + 1));  // +1 self-loop; always > 0
}

// ---------------- scan (CSR offsets) ----------------
#define SCAN_T 256
#define SCAN_V 4
#define SCAN_CHUNK 1024

__global__ void k_scan_partial(const int* __restrict__ counts, int N, int* __restrict__ blocksum) {
    __shared__ int sd[SCAN_T];
    int b = blockIdx.x, t = threadIdx.x;
    int base = b * SCAN_CHUNK + t * SCAN_V;
    int s = 0;
#pragma unroll
    for (int i = 0; i < SCAN_V; i++) { int idx = base + i; s += (idx < N) ? counts[idx] : 0; }
    sd[t] = s; __syncthreads();
    for (int off = 128; off > 0; off >>= 1) {
        if (t < off) sd[t] += sd[t + off];
        __syncthreads();
    }
    if (t == 0) blocksum[b] = sd[0];
}

__global__ void k_scan_block(int* __restrict__ blocksum, int nb) {
    if (threadIdx.x == 0 && blockIdx.x == 0) {
        int run = 0;
        for (int i = 0; i < nb; i++) { int v = blocksum[i]; blocksum[i] = run; run += v; }
        blocksum[nb] = run;
    }
}

__global__ void k_scan_final(const int* __restrict__ counts, int N, const int* __restrict__ blocksum,
                             int* __restrict__ offsets, int* __restrict__ cursor) {
    __shared__ int sd[SCAN_T];
    int b = blockIdx.x, t = threadIdx.x;
    int base = b * SCAN_CHUNK + t * SCAN_V;
    int v[SCAN_V]; int s = 0;
#pragma unroll
    for (int i = 0; i < SCAN_V; i++) { int idx = base + i; v[i] = (idx < N) ? counts[idx] : 0; s += v[i]; }
    sd[t] = s; __syncthreads();
    for (int off = 1; off < SCAN_T; off <<= 1) {  // Hillis-Steele inclusive
        int tmp = (t >= off) ? sd[t - off] : 0;
        __syncthreads();
        sd[t] += tmp;
        __syncthreads();
    }
    int ex = sd[t] - s + blocksum[b];
#pragma unroll
    for (int i = 0; i < SCAN_V; i++) {
        int idx = base + i;
        if (idx < N) { offsets[idx] = ex; cursor[idx] = ex; ex += v[i]; }
    }
    if (b == 0 && t == 0) offsets[N] = blocksum[gridDim.x];
}

__global__ void k_fill(const int* __restrict__ src, const int* __restrict__ dst, int E,
                       int* __restrict__ cursor, int* __restrict__ col) {
    int e = blockIdx.x * 256 + threadIdx.x;
    if (e < E) {
        int d = dst[e];
        int p = atomicAdd(&cursor[d], 1);
        col[p] = src[e];
    }
}

// ---------------- GEMM1: y1 = (x @ W1) * dinv[row] ----------------
__launch_bounds__(256)
__global__ void k_gemm1(const float* __restrict__ A, const float* __restrict__ B,
                        const float* __restrict__ dinv, float* __restrict__ Y, int M) {
    const int BM = 64, BN = 128, BK = 32, TM = 4, TN = 8;
    __shared__ float As[BM][BK + 4];   // 64x36
    __shared__ float Bs[BK][BN];       // 32x128
    int t = threadIdx.x;
    int tx = t & 15;   // col group
    int ty = t >> 4;   // row group
    int row0 = blockIdx.x * BM;
    float acc[TM][TN];
#pragma unroll
    for (int i = 0; i < TM; i++)
#pragma unroll
        for (int j = 0; j < TN; j++) acc[i][j] = 0.f;

    int am = t >> 2;         // 0..63 row in tile
    int ak = (t & 3) * 4;    // float4 col, +16 second half
    int bk = t >> 5;         // 0..7, +8 per iter
    int bn = (t & 31) * 4;

    for (int k0 = 0; k0 < F_IN; k0 += BK) {
#pragma unroll
        for (int h = 0; h < 2; h++) {
            int kk = ak + h * 16;
            int row = row0 + am;
            float4 v = (row < M) ? *(const float4*)(A + (size_t)row * F_IN + k0 + kk)
                                 : make_float4(0.f, 0.f, 0.f, 0.f);
            As[am][kk + 0] = v.x; As[am][kk + 1] = v.y; As[am][kk + 2] = v.z; As[am][kk + 3] = v.w;
        }
#pragma unroll
        for (int h = 0; h < 4; h++) {
            int kk = bk + h * 8;
            *(float4*)&Bs[kk][bn] = *(const float4*)(B + (size_t)(k0 + kk) * BN + bn);
        }
        __syncthreads();
#pragma unroll
        for (int kk = 0; kk < BK; kk++) {
            float a[TM], bv[TN];
#pragma unroll
            for (int i = 0; i < TM; i++) a[i] = As[ty * TM + i][kk];
#pragma unroll
            for (int j = 0; j < TN; j++) bv[j] = Bs[kk][tx * TN + j];
#pragma unroll
            for (int i = 0; i < TM; i++)
#pragma unroll
                for (int j = 0; j < TN; j++) acc[i][j] = fmaf(a[i], bv[j], acc[i][j]);
        }
        __syncthreads();
    }
#pragma unroll
    for (int i = 0; i < TM; i++) {
        int row = row0 + ty * TM + i;
        if (row < M) {
            float d = dinv[row];
            float4 o0 = make_float4(acc[i][0] * d, acc[i][1] * d, acc[i][2] * d, acc[i][3] * d);
            float4 o1 = make_float4(acc[i][4] * d, acc[i][5] * d, acc[i][6] * d, acc[i][7] * d);
            *(float4*)(Y + (size_t)row * HID + tx * TN) = o0;
            *(float4*)(Y + (size_t)row * HID + tx * TN + 4) = o1;
        }
    }
}

// ---------------- GEMM2: y2 = (hid @ W2) * dinv[row] ----------------
__launch_bounds__(256)
__global__ void k_gemm2(const float* __restrict__ A, const float* __restrict__ B,
                        const float* __restrict__ dinv, float* __restrict__ Y, int M) {
    const int BM = 128, BK = 32, TM = 4, TN = 5;
    __shared__ float As[BM][BK + 4];    // 128x36
    __shared__ float Bs[BK][C_OUT];     // 32x40
    int t = threadIdx.x;
    int tx = t & 7;   // col group (5 cols each)
    int ty = t >> 3;  // row group (4 rows each)
    int row0 = blockIdx.x * BM;
    float acc[TM][TN];
#pragma unroll
    for (int i = 0; i < TM; i++)
#pragma unroll
        for (int j = 0; j < TN; j++) acc[i][j] = 0.f;

    int am = t >> 1;  // 0..127

    for (int k0 = 0; k0 < HID; k0 += BK) {
#pragma unroll
        for (int h = 0; h < 4; h++) {
            int kq = (t & 1) + h * 2;   // 0..7 float4 within BK
            int row = row0 + am;
            float4 v = (row < M) ? *(const float4*)(A + (size_t)row * HID + k0 + kq * 4)
                                 : make_float4(0.f, 0.f, 0.f, 0.f);
            As[am][kq * 4 + 0] = v.x; As[am][kq * 4 + 1] = v.y;
            As[am][kq * 4 + 2] = v.z; As[am][kq * 4 + 3] = v.w;
        }
        for (int l = t; l < BK * (C_OUT / 4); l += 256) {
            int kk = l / (C_OUT / 4), q = l % (C_OUT / 4);
            *(float4*)&Bs[kk][q * 4] = *(const float4*)(B + (size_t)(k0 + kk) * C_OUT + q * 4);
        }
        __syncthreads();
#pragma unroll
        for (int kk = 0; kk < BK; kk++) {
            float a[TM], bv[TN];
#pragma unroll
            for (int i = 0; i < TM; i++) a[i] = As[ty * TM + i][kk];
#pragma unroll
            for (int j = 0; j < TN; j++) bv[j] = Bs[kk][tx * TN + j];
#pragma unroll
            for (int i = 0; i < TM; i++)
#pragma unroll
                for (int j = 0; j < TN; j++) acc[i][j] = fmaf(a[i], bv[j], acc[i][j]);
        }
        __syncthreads();
    }
#pragma unroll
    for (int i = 0; i < TM; i++) {
        int row = row0 + ty * TM + i;
        if (row < M) {
            float d = dinv[row];
#pragma unroll
            for (int j = 0; j < TN; j++) Y[(size_t)row * C_OUT + tx * TN + j] = acc[i][j] * d;
        }
    }
}

// ---------------- agg1: hid = relu(dinv*(sum_neigh y1 + y1_self) + b1) ----------------
__launch_bounds__(256)
__global__ void k_agg1(const float* __restrict__ y1, const int* __restrict__ col,
                       const int* __restrict__ offsets, const float* __restrict__ dinv,
                       const float* __restrict__ b1, float* __restrict__ hid, int N) {
    int w = threadIdx.x >> 6;
    int lane = threadIdx.x & 63;
    int node = blockIdx.x * 4 + w;
    if (node >= N) return;
    int s = offsets[node], e = offsets[node + 1];
    float2 acc = ((const float2*)(y1 + (size_t)node * HID))[lane];  // self-loop term
    for (int t0 = s; t0 < e; t0 += 64) {
        int cnt = e - t0; if (cnt > 64) cnt = 64;
        int j = (lane < cnt) ? col[t0 + lane] : 0;
        int u = 0;
        for (; u + 4 <= cnt; u += 4) {   // 4-way unroll: keep 4 loads in flight
            int j0 = __shfl(j, u + 0), j1 = __shfl(j, u + 1);
            int j2 = __shfl(j, u + 2), j3 = __shfl(j, u + 3);
            float2 v0 = ((const float2*)(y1 + (size_t)j0 * HID))[lane];
            float2 v1 = ((const float2*)(y1 + (size_t)j1 * HID))[lane];
            float2 v2 = ((const float2*)(y1 + (size_t)j2 * HID))[lane];
            float2 v3 = ((const float2*)(y1 + (size_t)j3 * HID))[lane];
            acc.x += v0.x + v1.x + v2.x + v3.x;
            acc.y += v0.y + v1.y + v2.y + v3.y;
        }
        for (; u < cnt; ++u) {
            int jj = __shfl(j, u);
            float2 v = ((const float2*)(y1 + (size_t)jj * HID))[lane];
            acc.x += v.x; acc.y += v.y;
        }
    }
    float d = dinv[node];
    float2 bb = ((const float2*)b1)[lane];
    float ox = fmaxf(fmaf(d, acc.x, bb.x), 0.f);
    float oy = fmaxf(fmaf(d, acc.y, bb.y), 0.f);
    ((float2*)(hid + (size_t)node * HID))[lane] = make_float2(ox, oy);
}

// ---------------- agg2 + bias + log_softmax fused ----------------
__launch_bounds__(256)
__global__ void k_agg2(const float* __restrict__ y2, const int* __restrict__ col,
                       const int* __restrict__ offsets, const float* __restrict__ dinv,
                       const float* __restrict__ b2, float* __restrict__ x2out,
                       float* __restrict__ logp, int N) {
    int w = threadIdx.x >> 6;
    int lane = threadIdx.x & 63;
    int node = blockIdx.x * 4 + w;
    if (node >= N) return;
    int s = offsets[node], e = offsets[node + 1];
    bool act = lane < C_OUT;
    float acc = act ? y2[(size_t)node * C_OUT + lane] : 0.f;  // self-loop term
    for (int t0 = s; t0 < e; t0 += 64) {
        int cnt = e - t0; if (cnt > 64) cnt = 64;
        int j = (lane < cnt) ? col[t0 + lane] : 0;
        int u = 0;
        for (; u + 4 <= cnt; u += 4) {
            int j0 = __shfl(j, u + 0), j1 = __shfl(j, u + 1);
            int j2 = __shfl(j, u + 2), j3 = __shfl(j, u + 3);
            float v0 = act ? y2[(size_t)j0 * C_OUT + lane] : 0.f;
            float v1 = act ? y2[(size_t)j1 * C_OUT + lane] : 0.f;
            float v2 = act ? y2[(size_t)j2 * C_OUT + lane] : 0.f;
            float v3 = act ? y2[(size_t)j3 * C_OUT + lane] : 0.f;
            acc += v0 + v1 + v2 + v3;
        }
        for (; u < cnt; ++u) {
            int jj = __shfl(j, u);
            if (act) acc += y2[(size_t)jj * C_OUT + lane];
        }
    }
    float d = dinv[node];
    float x2 = act ? fmaf(d, acc, b2[lane]) : -INFINITY;
    if (act) x2out[(size_t)node * C_OUT + lane] = x2;
    float m = x2;
#pragma unroll
    for (int off = 32; off > 0; off >>= 1) m = fmaxf(m, __shfl_xor(m, off));
    float ex = act ? expf(x2 - m) : 0.f;
    float sum = ex;
#pragma unroll
    for (int off = 32; off > 0; off >>= 1) sum += __shfl_xor(sum, off);
    if (act) logp[(size_t)node * C_OUT + lane] = x2 - m - logf(sum);
}

// ---------------- launcher ----------------
extern "C" void kernel_launch(void* const* d_in, const int* in_sizes, int n_in,
                              void* d_out, int out_size, void* d_ws, size_t ws_size,
                              hipStream_t stream) {
    const float* x  = (const float*)d_in[0];
    const int*   ei = (const int*)d_in[1];
    const float* W1 = (const float*)d_in[2];
    const float* b1 = (const float*)d_in[3];
    const float* W2 = (const float*)d_in[4];
    const float* b2 = (const float*)d_in[5];
    const int N = N_NODES;
    const int E = in_sizes[1] / 2;
    const int* src = ei;
    const int* dst = ei + E;

    float* out_hid  = (float*)d_out;                       // N*128
    float* out_x2   = out_hid + (size_t)N * HID;           // N*40
    float* out_logp = out_x2 + (size_t)N * C_OUT;          // N*40

    char* p = (char*)d_ws;
    auto alloc = [&](size_t bytes) { void* r = (void*)p; p += (bytes + 255) & ~255ull; return r; };
    int*   counts   = (int*)alloc((size_t)N * 4);
    int*   offsets  = (int*)alloc((size_t)(N + 1) * 4);
    int*   cursor   = (int*)alloc((size_t)N * 4);
    int*   blocksum = (int*)alloc(256 * 4);
    float* dinv     = (float*)alloc((size_t)N * 4);
    int*   col      = (int*)alloc((size_t)E * 4);
    float* y1       = (float*)alloc((size_t)N * HID * 4);
    float* y2       = (float*)alloc((size_t)N * C_OUT * 4);

    hipMemsetAsync(counts, 0, (size_t)N * 4, stream);
    k_deg<<<(E + 255) / 256, 256, 0, stream>>>(dst, E, counts);
    k_dinv<<<(N + 255) / 256, 256, 0, stream>>>(counts, dinv, N);
    int nb = (N + SCAN_CHUNK - 1) / SCAN_CHUNK;
    k_scan_partial<<<nb, SCAN_T, 0, stream>>>(counts, N, blocksum);
    k_scan_block<<<1, 64, 0, stream>>>(blocksum, nb);
    k_scan_final<<<nb, SCAN_T, 0, stream>>>(counts, N, blocksum, offsets, cursor);
    k_fill<<<(E + 255) / 256, 256, 0, stream>>>(src, dst, E, cursor, col);
    k_gemm1<<<(N + 63) / 64, 256, 0, stream>>>(x, W1, dinv, y1, N);
    k_agg1<<<(N + 3) / 4, 256, 0, stream>>>(y1, col, offsets, dinv, b1, out_hid, N);
    k_gemm2<<<(N + 127) / 128, 256, 0, stream>>>(out_hid, W2, dinv, y2, N);
    k_agg2<<<(N + 3) / 4, 256, 0, stream>>>(y2, col, offsets, dinv, b2, out_x2, out_logp, N);
}

// Round 2
// 370.794 us; speedup vs baseline: 1.3840x; 1.3840x over previous
//
#include <hip/hip_runtime.h>
#include <math.h>

#define N_NODES 50000
#define F_IN 256
#define HID 128
#define C_OUT 40
#define BINS ((N_NODES + 255) / 256)   // 196 buckets of 256 nodes

// ---------------- phase 1: bucket histogram ----------------
__global__ void k_hist(const int* __restrict__ dst, int E, int* __restrict__ binCount) {
    __shared__ int h[BINS];
    for (int i = threadIdx.x; i < BINS; i += 256) h[i] = 0;
    __syncthreads();
    for (int e = blockIdx.x * 256 + threadIdx.x; e < E; e += gridDim.x * 256)
        atomicAdd(&h[dst[e] >> 8], 1);
    __syncthreads();
    for (int i = threadIdx.x; i < BINS; i += 256)
        if (h[i]) atomicAdd(&binCount[i], h[i]);
}

// ---------------- phase 2: scan buckets ----------------
__global__ void k_scan_bins(const int* __restrict__ binCount, int* __restrict__ bucketBase,
                            int* __restrict__ binCursor, int* __restrict__ offsets, int E) {
    __shared__ int sd[256];
    int t = threadIdx.x;
    int v = (t < BINS) ? binCount[t] : 0;
    sd[t] = v; __syncthreads();
    for (int off = 1; off < 256; off <<= 1) {
        int tmp = (t >= off) ? sd[t - off] : 0;
        __syncthreads();
        sd[t] += tmp;
        __syncthreads();
    }
    int ex = sd[t] - v;
    if (t < BINS) { bucketBase[t] = ex; binCursor[t] = ex; }
    if (t == 0) { bucketBase[BINS] = E; offsets[N_NODES] = E; }
}

// ---------------- phase 3: partition edges into buckets ----------------
#define PCHUNK 8192
#define PTHREADS 512
__launch_bounds__(PTHREADS)
__global__ void k_partition(const int* __restrict__ src, const int* __restrict__ dst, int E,
                            int* __restrict__ binCursor, unsigned int* __restrict__ packed) {
    __shared__ unsigned int lpack[PCHUNK];   // (local_dst<<16)|src
    __shared__ unsigned int lpos[PCHUNK];    // (rank<<8)|bin
    __shared__ int lcnt[BINS];
    __shared__ int lrun[BINS];
    int t = threadIdx.x;
    int base = blockIdx.x * PCHUNK;
    int n = E - base; if (n > PCHUNK) n = PCHUNK;
    for (int i = t; i < BINS; i += PTHREADS) lcnt[i] = 0;
    __syncthreads();
    for (int i = t; i < n; i += PTHREADS) {
        int d = dst[base + i], s = src[base + i];
        int bin = d >> 8;
        unsigned int r = (unsigned int)atomicAdd(&lcnt[bin], 1);
        lpack[i] = ((unsigned int)(d & 255) << 16) | (unsigned int)s;
        lpos[i] = (r << 8) | (unsigned int)bin;
    }
    __syncthreads();
    if (t < BINS && lcnt[t] > 0) lrun[t] = atomicAdd(&binCursor[t], lcnt[t]);
    __syncthreads();
    for (int i = t; i < n; i += PTHREADS) {
        unsigned int p = lpos[i];
        int bin = p & 255;
        unsigned int r = p >> 8;
        packed[(size_t)lrun[bin] + r] = lpack[i];
    }
}

// ---------------- phase 4: per-bucket CSR (offsets, dinv, col) ----------------
__launch_bounds__(256)
__global__ void k_bucket_csr(const unsigned int* __restrict__ packed, const int* __restrict__ bucketBase,
                             int* __restrict__ offsets, float* __restrict__ dinv,
                             unsigned short* __restrict__ col, int N) {
    __shared__ int lcnt[256];
    __shared__ int lscan[256];
    __shared__ int lofs[256];
    int b = blockIdx.x, t = threadIdx.x;
    int s = bucketBase[b], e = bucketBase[b + 1];
    lcnt[t] = 0;
    __syncthreads();
    for (int i = s + t; i < e; i += 256) atomicAdd(&lcnt[packed[i] >> 16], 1);
    __syncthreads();
    int v = lcnt[t];
    lscan[t] = v;
    __syncthreads();
    for (int off = 1; off < 256; off <<= 1) {
        int tmp = (t >= off) ? lscan[t - off] : 0;
        __syncthreads();
        lscan[t] += tmp;
        __syncthreads();
    }
    int ex = lscan[t] - v;
    int node = b * 256 + t;
    if (node < N) {
        offsets[node] = s + ex;
        dinv[node] = rsqrtf((float)(v + 1));   // deg incl. self-loop
    }
    __syncthreads();
    lofs[t] = ex;
    lcnt[t] = 0;
    __syncthreads();
    for (int i = s + t; i < e; i += 256) {
        unsigned int p = packed[i];
        int ld = (int)(p >> 16);
        int r = atomicAdd(&lcnt[ld], 1);
        col[(size_t)s + lofs[ld] + r] = (unsigned short)(p & 0xFFFFu);
    }
}

// ---------------- GEMM1: y1 = (x @ W1) * dinv[row] ----------------
__launch_bounds__(256)
__global__ void k_gemm1(const float* __restrict__ A, const float* __restrict__ B,
                        const float* __restrict__ dinv, float* __restrict__ Y, int M) {
    const int BM = 64, BN = 128, BK = 32, TM = 4, TN = 8;
    __shared__ float As[BM][BK + 4];
    __shared__ float Bs[BK][BN];
    int t = threadIdx.x;
    int tx = t & 15;
    int ty = t >> 4;
    int row0 = blockIdx.x * BM;
    float acc[TM][TN];
#pragma unroll
    for (int i = 0; i < TM; i++)
#pragma unroll
        for (int j = 0; j < TN; j++) acc[i][j] = 0.f;

    int am = t >> 2;
    int ak = (t & 3) * 4;
    int bk = t >> 5;
    int bn = (t & 31) * 4;

    for (int k0 = 0; k0 < F_IN; k0 += BK) {
#pragma unroll
        for (int h = 0; h < 2; h++) {
            int kk = ak + h * 16;
            int row = row0 + am;
            float4 v = (row < M) ? *(const float4*)(A + (size_t)row * F_IN + k0 + kk)
                                 : make_float4(0.f, 0.f, 0.f, 0.f);
            As[am][kk + 0] = v.x; As[am][kk + 1] = v.y; As[am][kk + 2] = v.z; As[am][kk + 3] = v.w;
        }
#pragma unroll
        for (int h = 0; h < 4; h++) {
            int kk = bk + h * 8;
            *(float4*)&Bs[kk][bn] = *(const float4*)(B + (size_t)(k0 + kk) * BN + bn);
        }
        __syncthreads();
#pragma unroll
        for (int kk = 0; kk < BK; kk++) {
            float a[TM], bv[TN];
#pragma unroll
            for (int i = 0; i < TM; i++) a[i] = As[ty * TM + i][kk];
#pragma unroll
            for (int j = 0; j < TN; j++) bv[j] = Bs[kk][tx * TN + j];
#pragma unroll
            for (int i = 0; i < TM; i++)
#pragma unroll
                for (int j = 0; j < TN; j++) acc[i][j] = fmaf(a[i], bv[j], acc[i][j]);
        }
        __syncthreads();
    }
#pragma unroll
    for (int i = 0; i < TM; i++) {
        int row = row0 + ty * TM + i;
        if (row < M) {
            float d = dinv[row];
            float4 o0 = make_float4(acc[i][0] * d, acc[i][1] * d, acc[i][2] * d, acc[i][3] * d);
            float4 o1 = make_float4(acc[i][4] * d, acc[i][5] * d, acc[i][6] * d, acc[i][7] * d);
            *(float4*)(Y + (size_t)row * HID + tx * TN) = o0;
            *(float4*)(Y + (size_t)row * HID + tx * TN + 4) = o1;
        }
    }
}

// ---------------- GEMM2: y2 = (hid @ W2) * dinv[row] ----------------
__launch_bounds__(256)
__global__ void k_gemm2(const float* __restrict__ A, const float* __restrict__ B,
                        const float* __restrict__ dinv, float* __restrict__ Y, int M) {
    const int BM = 128, BK = 32, TM = 4, TN = 5;
    __shared__ float As[BM][BK + 4];
    __shared__ float Bs[BK][C_OUT];
    int t = threadIdx.x;
    int tx = t & 7;
    int ty = t >> 3;
    int row0 = blockIdx.x * BM;
    float acc[TM][TN];
#pragma unroll
    for (int i = 0; i < TM; i++)
#pragma unroll
        for (int j = 0; j < TN; j++) acc[i][j] = 0.f;

    int am = t >> 1;

    for (int k0 = 0; k0 < HID; k0 += BK) {
#pragma unroll
        for (int h = 0; h < 4; h++) {
            int kq = (t & 1) + h * 2;
            int row = row0 + am;
            float4 v = (row < M) ? *(const float4*)(A + (size_t)row * HID + k0 + kq * 4)
                                 : make_float4(0.f, 0.f, 0.f, 0.f);
            As[am][kq * 4 + 0] = v.x; As[am][kq * 4 + 1] = v.y;
            As[am][kq * 4 + 2] = v.z; As[am][kq * 4 + 3] = v.w;
        }
        for (int l = t; l < BK * (C_OUT / 4); l += 256) {
            int kk = l / (C_OUT / 4), q = l % (C_OUT / 4);
            *(float4*)&Bs[kk][q * 4] = *(const float4*)(B + (size_t)(k0 + kk) * C_OUT + q * 4);
        }
        __syncthreads();
#pragma unroll
        for (int kk = 0; kk < BK; kk++) {
            float a[TM], bv[TN];
#pragma unroll
            for (int i = 0; i < TM; i++) a[i] = As[ty * TM + i][kk];
#pragma unroll
            for (int j = 0; j < TN; j++) bv[j] = Bs[kk][tx * TN + j];
#pragma unroll
            for (int i = 0; i < TM; i++)
#pragma unroll
                for (int j = 0; j < TN; j++) acc[i][j] = fmaf(a[i], bv[j], acc[i][j]);
        }
        __syncthreads();
    }
#pragma unroll
    for (int i = 0; i < TM; i++) {
        int row = row0 + ty * TM + i;
        if (row < M) {
            float d = dinv[row];
#pragma unroll
            for (int j = 0; j < TN; j++) Y[(size_t)row * C_OUT + tx * TN + j] = acc[i][j] * d;
        }
    }
}

// ---------------- agg1: hid = relu(dinv*(sum_neigh y1 + y1_self) + b1) ----------------
__launch_bounds__(256)
__global__ void k_agg1(const float* __restrict__ y1, const unsigned short* __restrict__ col,
                       const int* __restrict__ offsets, const float* __restrict__ dinv,
                       const float* __restrict__ b1, float* __restrict__ hid, int N) {
    int w = threadIdx.x >> 6;
    int lane = threadIdx.x & 63;
    int node = blockIdx.x * 4 + w;
    if (node >= N) return;
    int s = offsets[node], e = offsets[node + 1];
    float2 acc = ((const float2*)(y1 + (size_t)node * HID))[lane];  // self-loop term
    for (int t0 = s; t0 < e; t0 += 64) {
        int cnt = e - t0; if (cnt > 64) cnt = 64;
        int j = (lane < cnt) ? (int)col[t0 + lane] : 0;
        int u = 0;
        for (; u + 4 <= cnt; u += 4) {
            int j0 = __shfl(j, u + 0), j1 = __shfl(j, u + 1);
            int j2 = __shfl(j, u + 2), j3 = __shfl(j, u + 3);
            float2 v0 = ((const float2*)(y1 + (size_t)j0 * HID))[lane];
            float2 v1 = ((const float2*)(y1 + (size_t)j1 * HID))[lane];
            float2 v2 = ((const float2*)(y1 + (size_t)j2 * HID))[lane];
            float2 v3 = ((const float2*)(y1 + (size_t)j3 * HID))[lane];
            acc.x += v0.x + v1.x + v2.x + v3.x;
            acc.y += v0.y + v1.y + v2.y + v3.y;
        }
        for (; u < cnt; ++u) {
            int jj = __shfl(j, u);
            float2 v = ((const float2*)(y1 + (size_t)jj * HID))[lane];
            acc.x += v.x; acc.y += v.y;
        }
    }
    float d = dinv[node];
    float2 bb = ((const float2*)b1)[lane];
    float ox = fmaxf(fmaf(d, acc.x, bb.x), 0.f);
    float oy = fmaxf(fmaf(d, acc.y, bb.y), 0.f);
    ((float2*)(hid + (size_t)node * HID))[lane] = make_float2(ox, oy);
}

// ---------------- agg2 + bias + log_softmax fused ----------------
__launch_bounds__(256)
__global__ void k_agg2(const float* __restrict__ y2, const unsigned short* __restrict__ col,
                       const int* __restrict__ offsets, const float* __restrict__ dinv,
                       const float* __restrict__ b2, float* __restrict__ x2out,
                       float* __restrict__ logp, int N) {
    int w = threadIdx.x >> 6;
    int lane = threadIdx.x & 63;
    int node = blockIdx.x * 4 + w;
    if (node >= N) return;
    int s = offsets[node], e = offsets[node + 1];
    bool act = lane < C_OUT;
    float acc = act ? y2[(size_t)node * C_OUT + lane] : 0.f;  // self-loop term
    for (int t0 = s; t0 < e; t0 += 64) {
        int cnt = e - t0; if (cnt > 64) cnt = 64;
        int j = (lane < cnt) ? (int)col[t0 + lane] : 0;
        int u = 0;
        for (; u + 4 <= cnt; u += 4) {
            int j0 = __shfl(j, u + 0), j1 = __shfl(j, u + 1);
            int j2 = __shfl(j, u + 2), j3 = __shfl(j, u + 3);
            float v0 = act ? y2[(size_t)j0 * C_OUT + lane] : 0.f;
            float v1 = act ? y2[(size_t)j1 * C_OUT + lane] : 0.f;
            float v2 = act ? y2[(size_t)j2 * C_OUT + lane] : 0.f;
            float v3 = act ? y2[(size_t)j3 * C_OUT + lane] : 0.f;
            acc += v0 + v1 + v2 + v3;
        }
        for (; u < cnt; ++u) {
            int jj = __shfl(j, u);
            if (act) acc += y2[(size_t)jj * C_OUT + lane];
        }
    }
    float d = dinv[node];
    float x2 = act ? fmaf(d, acc, b2[lane]) : -INFINITY;
    if (act) x2out[(size_t)node * C_OUT + lane] = x2;
    float m = x2;
#pragma unroll
    for (int off = 32; off > 0; off >>= 1) m = fmaxf(m, __shfl_xor(m, off));
    float ex = act ? expf(x2 - m) : 0.f;
    float sum = ex;
#pragma unroll
    for (int off = 32; off > 0; off >>= 1) sum += __shfl_xor(sum, off);
    if (act) logp[(size_t)node * C_OUT + lane] = x2 - m - logf(sum);
}

// ---------------- launcher ----------------
extern "C" void kernel_launch(void* const* d_in, const int* in_sizes, int n_in,
                              void* d_out, int out_size, void* d_ws, size_t ws_size,
                              hipStream_t stream) {
    const float* x  = (const float*)d_in[0];
    const int*   ei = (const int*)d_in[1];
    const float* W1 = (const float*)d_in[2];
    const float* b1 = (const float*)d_in[3];
    const float* W2 = (const float*)d_in[4];
    const float* b2 = (const float*)d_in[5];
    const int N = N_NODES;
    const int E = in_sizes[1] / 2;
    const int* src = ei;
    const int* dst = ei + E;

    float* out_hid  = (float*)d_out;                       // N*128
    float* out_x2   = out_hid + (size_t)N * HID;           // N*40
    float* out_logp = out_x2 + (size_t)N * C_OUT;          // N*40

    char* p = (char*)d_ws;
    auto alloc = [&](size_t bytes) { void* r = (void*)p; p += (bytes + 255) & ~255ull; return r; };
    int*   binCount   = (int*)alloc((size_t)BINS * 4);
    int*   bucketBase = (int*)alloc((size_t)(BINS + 1) * 4);
    int*   binCursor  = (int*)alloc((size_t)BINS * 4);
    int*   offsets    = (int*)alloc((size_t)(N + 1) * 4);
    float* dinv       = (float*)alloc((size_t)N * 4);
    unsigned int*   packed = (unsigned int*)alloc((size_t)E * 4);
    unsigned short* col    = (unsigned short*)alloc((size_t)E * 2);
    float* y1         = (float*)alloc((size_t)N * HID * 4);
    float* y2         = (float*)alloc((size_t)N * C_OUT * 4);

    hipMemsetAsync(binCount, 0, (size_t)BINS * 4, stream);
    k_hist<<<512, 256, 0, stream>>>(dst, E, binCount);
    k_scan_bins<<<1, 256, 0, stream>>>(binCount, bucketBase, binCursor, offsets, E);
    k_partition<<<(E + PCHUNK - 1) / PCHUNK, PTHREADS, 0, stream>>>(src, dst, E, binCursor, packed);
    k_bucket_csr<<<BINS, 256, 0, stream>>>(packed, bucketBase, offsets, dinv, col, N);
    k_gemm1<<<(N + 63) / 64, 256, 0, stream>>>(x, W1, dinv, y1, N);
    k_agg1<<<(N + 3) / 4, 256, 0, stream>>>(y1, col, offsets, dinv, b1, out_hid, N);
    k_gemm2<<<(N + 127) / 128, 256, 0, stream>>>(out_hid, W2, dinv, y2, N);
    k_agg2<<<(N + 3) / 4, 256, 0, stream>>>(y2, col, offsets, dinv, b2, out_x2, out_logp, N);
}

// Round 3
// 359.635 us; speedup vs baseline: 1.4270x; 1.0310x over previous
//
#include <hip/hip_runtime.h>
#include <math.h>

#define N_NODES 50000
#define F_IN 256
#define HID 128
#define C_OUT 40
#define BINS ((N_NODES + 255) / 256)   // 196 buckets of 256 nodes

__device__ __forceinline__ unsigned short f2bf(float f) {
    unsigned int u = __float_as_uint(f);
    unsigned int r = (u + 0x7FFFu + ((u >> 16) & 1u)) >> 16;
    return (unsigned short)r;
}
__device__ __forceinline__ float bf2f(unsigned short s) {
    return __uint_as_float((unsigned int)s << 16);
}

// ---------------- phase 1: bucket histogram ----------------
__global__ void k_hist(const int* __restrict__ dst, int E, int* __restrict__ binCount) {
    __shared__ int h[BINS];
    for (int i = threadIdx.x; i < BINS; i += 256) h[i] = 0;
    __syncthreads();
    for (int e = blockIdx.x * 256 + threadIdx.x; e < E; e += gridDim.x * 256)
        atomicAdd(&h[dst[e] >> 8], 1);
    __syncthreads();
    for (int i = threadIdx.x; i < BINS; i += 256)
        if (h[i]) atomicAdd(&binCount[i], h[i]);
}

// ---------------- phase 2: scan buckets ----------------
__global__ void k_scan_bins(const int* __restrict__ binCount, int* __restrict__ bucketBase,
                            int* __restrict__ binCursor, int* __restrict__ offsets, int E) {
    __shared__ int sd[256];
    int t = threadIdx.x;
    int v = (t < BINS) ? binCount[t] : 0;
    sd[t] = v; __syncthreads();
    for (int off = 1; off < 256; off <<= 1) {
        int tmp = (t >= off) ? sd[t - off] : 0;
        __syncthreads();
        sd[t] += tmp;
        __syncthreads();
    }
    int ex = sd[t] - v;
    if (t < BINS) { bucketBase[t] = ex; binCursor[t] = ex; }
    if (t == 0) { bucketBase[BINS] = E; offsets[N_NODES] = E; }
}

// ---------------- phase 3: partition edges into buckets ----------------
#define PCHUNK 8192
#define PTHREADS 512
__launch_bounds__(PTHREADS)
__global__ void k_partition(const int* __restrict__ src, const int* __restrict__ dst, int E,
                            int* __restrict__ binCursor, unsigned int* __restrict__ packed) {
    __shared__ unsigned int lpack[PCHUNK];   // (local_dst<<16)|src
    __shared__ unsigned int lpos[PCHUNK];    // (rank<<8)|bin
    __shared__ int lcnt[BINS];
    __shared__ int lrun[BINS];
    int t = threadIdx.x;
    int base = blockIdx.x * PCHUNK;
    int n = E - base; if (n > PCHUNK) n = PCHUNK;
    for (int i = t; i < BINS; i += PTHREADS) lcnt[i] = 0;
    __syncthreads();
    for (int i = t; i < n; i += PTHREADS) {
        int d = dst[base + i], s = src[base + i];
        int bin = d >> 8;
        unsigned int r = (unsigned int)atomicAdd(&lcnt[bin], 1);
        lpack[i] = ((unsigned int)(d & 255) << 16) | (unsigned int)s;
        lpos[i] = (r << 8) | (unsigned int)bin;
    }
    __syncthreads();
    if (t < BINS && lcnt[t] > 0) lrun[t] = atomicAdd(&binCursor[t], lcnt[t]);
    __syncthreads();
    for (int i = t; i < n; i += PTHREADS) {
        unsigned int p = lpos[i];
        int bin = p & 255;
        unsigned int r = p >> 8;
        packed[(size_t)lrun[bin] + r] = lpack[i];
    }
}

// ---------------- phase 4: per-bucket CSR (offsets, dinv, col) ----------------
__launch_bounds__(256)
__global__ void k_bucket_csr(const unsigned int* __restrict__ packed, const int* __restrict__ bucketBase,
                             int* __restrict__ offsets, float* __restrict__ dinv,
                             unsigned short* __restrict__ col, int N) {
    __shared__ int lcnt[256];
    __shared__ int lscan[256];
    __shared__ int lofs[256];
    int b = blockIdx.x, t = threadIdx.x;
    int s = bucketBase[b], e = bucketBase[b + 1];
    lcnt[t] = 0;
    __syncthreads();
    for (int i = s + t; i < e; i += 256) atomicAdd(&lcnt[packed[i] >> 16], 1);
    __syncthreads();
    int v = lcnt[t];
    lscan[t] = v;
    __syncthreads();
    for (int off = 1; off < 256; off <<= 1) {
        int tmp = (t >= off) ? lscan[t - off] : 0;
        __syncthreads();
        lscan[t] += tmp;
        __syncthreads();
    }
    int ex = lscan[t] - v;
    int node = b * 256 + t;
    if (node < N) {
        offsets[node] = s + ex;
        dinv[node] = rsqrtf((float)(v + 1));   // deg incl. self-loop
    }
    __syncthreads();
    lofs[t] = ex;
    lcnt[t] = 0;
    __syncthreads();
    for (int i = s + t; i < e; i += 256) {
        unsigned int p = packed[i];
        int ld = (int)(p >> 16);
        int r = atomicAdd(&lcnt[ld], 1);
        col[(size_t)s + lofs[ld] + r] = (unsigned short)(p & 0xFFFFu);
    }
}

// ---------------- GEMM1: y1b = bf16((x @ W1) * dinv[row]) ----------------
// As staged k-major with +4 pad: conflict-free staging writes, b128 fragment reads.
__launch_bounds__(256)
__global__ void k_gemm1(const float* __restrict__ A, const float* __restrict__ B,
                        const float* __restrict__ dinv, unsigned int* __restrict__ Yb, int M) {
    const int BM = 64, BN = 128, BK = 32, TM = 4, TN = 8;
    __shared__ float As[BK][BM + 4];   // k-major, 32x68
    __shared__ float Bs[BK][BN];       // 32x128
    int t = threadIdx.x;
    int tx = t & 15;   // col group (8 cols)
    int ty = t >> 4;   // row group (4 rows)
    int row0 = blockIdx.x * BM;
    float acc[TM][TN];
#pragma unroll
    for (int i = 0; i < TM; i++)
#pragma unroll
        for (int j = 0; j < TN; j++) acc[i][j] = 0.f;

    int am = t >> 2;         // 0..63 row in tile
    int ak = (t & 3) * 4;    // float4 k, +16 second half
    int bk = t >> 5;         // 0..7, +8 per iter
    int bn = (t & 31) * 4;

    for (int k0 = 0; k0 < F_IN; k0 += BK) {
#pragma unroll
        for (int h = 0; h < 2; h++) {
            int kk = ak + h * 16;
            int row = row0 + am;
            float4 v = (row < M) ? *(const float4*)(A + (size_t)row * F_IN + k0 + kk)
                                 : make_float4(0.f, 0.f, 0.f, 0.f);
            As[kk + 0][am] = v.x; As[kk + 1][am] = v.y; As[kk + 2][am] = v.z; As[kk + 3][am] = v.w;
        }
#pragma unroll
        for (int h = 0; h < 4; h++) {
            int kk = bk + h * 8;
            *(float4*)&Bs[kk][bn] = *(const float4*)(B + (size_t)(k0 + kk) * BN + bn);
        }
        __syncthreads();
#pragma unroll
        for (int kk = 0; kk < BK; kk++) {
            float4 a4 = *(const float4*)&As[kk][ty * TM];
            float4 b0 = *(const float4*)&Bs[kk][tx * TN];
            float4 b1 = *(const float4*)&Bs[kk][tx * TN + 4];
            float a[TM] = {a4.x, a4.y, a4.z, a4.w};
            float bv[TN] = {b0.x, b0.y, b0.z, b0.w, b1.x, b1.y, b1.z, b1.w};
#pragma unroll
            for (int i = 0; i < TM; i++)
#pragma unroll
                for (int j = 0; j < TN; j++) acc[i][j] = fmaf(a[i], bv[j], acc[i][j]);
        }
        __syncthreads();
    }
#pragma unroll
    for (int i = 0; i < TM; i++) {
        int row = row0 + ty * TM + i;
        if (row < M) {
            float d = dinv[row];
            uint4 o;
            o.x = (unsigned int)f2bf(acc[i][0] * d) | ((unsigned int)f2bf(acc[i][1] * d) << 16);
            o.y = (unsigned int)f2bf(acc[i][2] * d) | ((unsigned int)f2bf(acc[i][3] * d) << 16);
            o.z = (unsigned int)f2bf(acc[i][4] * d) | ((unsigned int)f2bf(acc[i][5] * d) << 16);
            o.w = (unsigned int)f2bf(acc[i][6] * d) | ((unsigned int)f2bf(acc[i][7] * d) << 16);
            *(uint4*)(Yb + (size_t)row * (HID / 2) + tx * (TN / 2)) = o;
        }
    }
}

// ---------------- GEMM2: y2b = bf16((hid @ W2) * dinv[row]) ----------------
__launch_bounds__(256)
__global__ void k_gemm2(const float* __restrict__ A, const float* __restrict__ B,
                        const float* __restrict__ dinv, unsigned short* __restrict__ Yb, int M) {
    const int BM = 128, BK = 32, TM = 4, TN = 5;
    __shared__ float As[BM][BK + 4];
    __shared__ float Bs[BK][C_OUT];
    int t = threadIdx.x;
    int tx = t & 7;
    int ty = t >> 3;
    int row0 = blockIdx.x * BM;
    float acc[TM][TN];
#pragma unroll
    for (int i = 0; i < TM; i++)
#pragma unroll
        for (int j = 0; j < TN; j++) acc[i][j] = 0.f;

    int am = t >> 1;

    for (int k0 = 0; k0 < HID; k0 += BK) {
#pragma unroll
        for (int h = 0; h < 4; h++) {
            int kq = (t & 1) + h * 2;
            int row = row0 + am;
            float4 v = (row < M) ? *(const float4*)(A + (size_t)row * HID + k0 + kq * 4)
                                 : make_float4(0.f, 0.f, 0.f, 0.f);
            As[am][kq * 4 + 0] = v.x; As[am][kq * 4 + 1] = v.y;
            As[am][kq * 4 + 2] = v.z; As[am][kq * 4 + 3] = v.w;
        }
        for (int l = t; l < BK * (C_OUT / 4); l += 256) {
            int kk = l / (C_OUT / 4), q = l % (C_OUT / 4);
            *(float4*)&Bs[kk][q * 4] = *(const float4*)(B + (size_t)(k0 + kk) * C_OUT + q * 4);
        }
        __syncthreads();
#pragma unroll
        for (int kk = 0; kk < BK; kk++) {
            float a[TM], bv[TN];
#pragma unroll
            for (int i = 0; i < TM; i++) a[i] = As[ty * TM + i][kk];
#pragma unroll
            for (int j = 0; j < TN; j++) bv[j] = Bs[kk][tx * TN + j];
#pragma unroll
            for (int i = 0; i < TM; i++)
#pragma unroll
                for (int j = 0; j < TN; j++) acc[i][j] = fmaf(a[i], bv[j], acc[i][j]);
        }
        __syncthreads();
    }
#pragma unroll
    for (int i = 0; i < TM; i++) {
        int row = row0 + ty * TM + i;
        if (row < M) {
            float d = dinv[row];
#pragma unroll
            for (int j = 0; j < TN; j++)
                Yb[(size_t)row * C_OUT + tx * TN + j] = f2bf(acc[i][j] * d);
        }
    }
}

// ---------------- agg1: hid = relu(dinv*(sum_neigh y1 + y1_self) + b1) ----------------
// y1 gathered as bf16 (uint = 2 features); accumulate f32.
__launch_bounds__(256)
__global__ void k_agg1(const unsigned int* __restrict__ y1b, const unsigned short* __restrict__ col,
                       const int* __restrict__ offsets, const float* __restrict__ dinv,
                       const float* __restrict__ b1, float* __restrict__ hid, int N) {
    int w = threadIdx.x >> 6;
    int lane = threadIdx.x & 63;
    int node = blockIdx.x * 4 + w;
    if (node >= N) return;
    int s = offsets[node], e = offsets[node + 1];
    unsigned int sv = y1b[(size_t)node * 64 + lane];           // self-loop term
    float accx = __uint_as_float(sv << 16);
    float accy = __uint_as_float(sv & 0xFFFF0000u);
    for (int t0 = s; t0 < e; t0 += 64) {
        int cnt = e - t0; if (cnt > 64) cnt = 64;
        int j = (lane < cnt) ? (int)col[t0 + lane] : 0;
        int u = 0;
        for (; u + 4 <= cnt; u += 4) {
            int j0 = __shfl(j, u + 0), j1 = __shfl(j, u + 1);
            int j2 = __shfl(j, u + 2), j3 = __shfl(j, u + 3);
            unsigned int v0 = y1b[(size_t)j0 * 64 + lane];
            unsigned int v1 = y1b[(size_t)j1 * 64 + lane];
            unsigned int v2 = y1b[(size_t)j2 * 64 + lane];
            unsigned int v3 = y1b[(size_t)j3 * 64 + lane];
            accx += __uint_as_float(v0 << 16) + __uint_as_float(v1 << 16)
                  + __uint_as_float(v2 << 16) + __uint_as_float(v3 << 16);
            accy += __uint_as_float(v0 & 0xFFFF0000u) + __uint_as_float(v1 & 0xFFFF0000u)
                  + __uint_as_float(v2 & 0xFFFF0000u) + __uint_as_float(v3 & 0xFFFF0000u);
        }
        for (; u < cnt; ++u) {
            int jj = __shfl(j, u);
            unsigned int v = y1b[(size_t)jj * 64 + lane];
            accx += __uint_as_float(v << 16);
            accy += __uint_as_float(v & 0xFFFF0000u);
        }
    }
    float d = dinv[node];
    float2 bb = ((const float2*)b1)[lane];
    float ox = fmaxf(fmaf(d, accx, bb.x), 0.f);
    float oy = fmaxf(fmaf(d, accy, bb.y), 0.f);
    ((float2*)(hid + (size_t)node * HID))[lane] = make_float2(ox, oy);
}

// ---------------- agg2 + bias + log_softmax fused ----------------
__launch_bounds__(256)
__global__ void k_agg2(const unsigned short* __restrict__ y2b, const unsigned short* __restrict__ col,
                       const int* __restrict__ offsets, const float* __restrict__ dinv,
                       const float* __restrict__ b2, float* __restrict__ x2out,
                       float* __restrict__ logp, int N) {
    int w = threadIdx.x >> 6;
    int lane = threadIdx.x & 63;
    int node = blockIdx.x * 4 + w;
    if (node >= N) return;
    int s = offsets[node], e = offsets[node + 1];
    bool act = lane < C_OUT;
    float acc = act ? bf2f(y2b[(size_t)node * C_OUT + lane]) : 0.f;  // self-loop term
    for (int t0 = s; t0 < e; t0 += 64) {
        int cnt = e - t0; if (cnt > 64) cnt = 64;
        int j = (lane < cnt) ? (int)col[t0 + lane] : 0;
        int u = 0;
        for (; u + 4 <= cnt; u += 4) {
            int j0 = __shfl(j, u + 0), j1 = __shfl(j, u + 1);
            int j2 = __shfl(j, u + 2), j3 = __shfl(j, u + 3);
            float v0 = act ? bf2f(y2b[(size_t)j0 * C_OUT + lane]) : 0.f;
            float v1 = act ? bf2f(y2b[(size_t)j1 * C_OUT + lane]) : 0.f;
            float v2 = act ? bf2f(y2b[(size_t)j2 * C_OUT + lane]) : 0.f;
            float v3 = act ? bf2f(y2b[(size_t)j3 * C_OUT + lane]) : 0.f;
            acc += v0 + v1 + v2 + v3;
        }
        for (; u < cnt; ++u) {
            int jj = __shfl(j, u);
            if (act) acc += bf2f(y2b[(size_t)jj * C_OUT + lane]);
        }
    }
    float d = dinv[node];
    float x2 = act ? fmaf(d, acc, b2[lane]) : -INFINITY;
    if (act) x2out[(size_t)node * C_OUT + lane] = x2;
    float m = x2;
#pragma unroll
    for (int off = 32; off > 0; off >>= 1) m = fmaxf(m, __shfl_xor(m, off));
    float ex = act ? expf(x2 - m) : 0.f;
    float sum = ex;
#pragma unroll
    for (int off = 32; off > 0; off >>= 1) sum += __shfl_xor(sum, off);
    if (act) logp[(size_t)node * C_OUT + lane] = x2 - m - logf(sum);
}

// ---------------- launcher ----------------
extern "C" void kernel_launch(void* const* d_in, const int* in_sizes, int n_in,
                              void* d_out, int out_size, void* d_ws, size_t ws_size,
                              hipStream_t stream) {
    const float* x  = (const float*)d_in[0];
    const int*   ei = (const int*)d_in[1];
    const float* W1 = (const float*)d_in[2];
    const float* b1 = (const float*)d_in[3];
    const float* W2 = (const float*)d_in[4];
    const float* b2 = (const float*)d_in[5];
    const int N = N_NODES;
    const int E = in_sizes[1] / 2;
    const int* src = ei;
    const int* dst = ei + E;

    float* out_hid  = (float*)d_out;                       // N*128
    float* out_x2   = out_hid + (size_t)N * HID;           // N*40
    float* out_logp = out_x2 + (size_t)N * C_OUT;          // N*40

    char* p = (char*)d_ws;
    auto alloc = [&](size_t bytes) { void* r = (void*)p; p += (bytes + 255) & ~255ull; return r; };
    int*   binCount   = (int*)alloc((size_t)BINS * 4);
    int*   bucketBase = (int*)alloc((size_t)(BINS + 1) * 4);
    int*   binCursor  = (int*)alloc((size_t)BINS * 4);
    int*   offsets    = (int*)alloc((size_t)(N + 1) * 4);
    float* dinv       = (float*)alloc((size_t)N * 4);
    unsigned int*   packed = (unsigned int*)alloc((size_t)E * 4);
    unsigned short* col    = (unsigned short*)alloc((size_t)E * 2);
    unsigned int*   y1b    = (unsigned int*)alloc((size_t)N * (HID / 2) * 4);   // bf16 x2 packed
    unsigned short* y2b    = (unsigned short*)alloc((size_t)N * C_OUT * 2);     // bf16

    hipMemsetAsync(binCount, 0, (size_t)BINS * 4, stream);
    k_hist<<<512, 256, 0, stream>>>(dst, E, binCount);
    k_scan_bins<<<1, 256, 0, stream>>>(binCount, bucketBase, binCursor, offsets, E);
    k_partition<<<(E + PCHUNK - 1) / PCHUNK, PTHREADS, 0, stream>>>(src, dst, E, binCursor, packed);
    k_bucket_csr<<<BINS, 256, 0, stream>>>(packed, bucketBase, offsets, dinv, col, N);
    k_gemm1<<<(N + 63) / 64, 256, 0, stream>>>(x, W1, dinv, y1b, N);
    k_agg1<<<(N + 3) / 4, 256, 0, stream>>>(y1b, col, offsets, dinv, b1, out_hid, N);
    k_gemm2<<<(N + 127) / 128, 256, 0, stream>>>(out_hid, W2, dinv, y2b, N);
    k_agg2<<<(N + 3) / 4, 256, 0, stream>>>(y2b, col, offsets, dinv, b2, out_x2, out_logp, N);
}

// Round 4
// 319.491 us; speedup vs baseline: 1.6063x; 1.1257x over previous
//
#include <hip/hip_runtime.h>
#include <math.h>

#define N_NODES 50000
#define F_IN 256
#define HID 128
#define C_OUT 40
#define BINS ((N_NODES + 255) / 256)   // 196 buckets of 256 nodes

__device__ __forceinline__ unsigned short f2bf(float f) {
    unsigned int u = __float_as_uint(f);
    unsigned int r = (u + 0x7FFFu + ((u >> 16) & 1u)) >> 16;
    return (unsigned short)r;
}
__device__ __forceinline__ float bf_lo(unsigned int u) { return __uint_as_float(u << 16); }
__device__ __forceinline__ float bf_hi(unsigned int u) { return __uint_as_float(u & 0xFFFF0000u); }

// ---------------- phase 1: bucket histogram ----------------
__global__ void k_hist(const int* __restrict__ dst, int E, int* __restrict__ binCount) {
    __shared__ int h[BINS];
    for (int i = threadIdx.x; i < BINS; i += 256) h[i] = 0;
    __syncthreads();
    for (int e = blockIdx.x * 256 + threadIdx.x; e < E; e += gridDim.x * 256)
        atomicAdd(&h[dst[e] >> 8], 1);
    __syncthreads();
    for (int i = threadIdx.x; i < BINS; i += 256)
        if (h[i]) atomicAdd(&binCount[i], h[i]);
}

// ---------------- phase 2: scan buckets ----------------
__global__ void k_scan_bins(const int* __restrict__ binCount, int* __restrict__ bucketBase,
                            int* __restrict__ binCursor, int* __restrict__ offsets, int E) {
    __shared__ int sd[256];
    int t = threadIdx.x;
    int v = (t < BINS) ? binCount[t] : 0;
    sd[t] = v; __syncthreads();
    for (int off = 1; off < 256; off <<= 1) {
        int tmp = (t >= off) ? sd[t - off] : 0;
        __syncthreads();
        sd[t] += tmp;
        __syncthreads();
    }
    int ex = sd[t] - v;
    if (t < BINS) { bucketBase[t] = ex; binCursor[t] = ex; }
    if (t == 0) { bucketBase[BINS] = E; offsets[N_NODES] = E; }
}

// ---------------- phase 3: partition edges into buckets ----------------
#define PCHUNK 8192
#define PTHREADS 512
__launch_bounds__(PTHREADS)
__global__ void k_partition(const int* __restrict__ src, const int* __restrict__ dst, int E,
                            int* __restrict__ binCursor, unsigned int* __restrict__ packed) {
    __shared__ unsigned int lpack[PCHUNK];   // (local_dst<<16)|src
    __shared__ unsigned int lpos[PCHUNK];    // (rank<<8)|bin
    __shared__ int lcnt[BINS];
    __shared__ int lrun[BINS];
    int t = threadIdx.x;
    int base = blockIdx.x * PCHUNK;
    int n = E - base; if (n > PCHUNK) n = PCHUNK;
    for (int i = t; i < BINS; i += PTHREADS) lcnt[i] = 0;
    __syncthreads();
    for (int i = t; i < n; i += PTHREADS) {
        int d = dst[base + i], s = src[base + i];
        int bin = d >> 8;
        unsigned int r = (unsigned int)atomicAdd(&lcnt[bin], 1);
        lpack[i] = ((unsigned int)(d & 255) << 16) | (unsigned int)s;
        lpos[i] = (r << 8) | (unsigned int)bin;
    }
    __syncthreads();
    if (t < BINS && lcnt[t] > 0) lrun[t] = atomicAdd(&binCursor[t], lcnt[t]);
    __syncthreads();
    for (int i = t; i < n; i += PTHREADS) {
        unsigned int p = lpos[i];
        int bin = p & 255;
        unsigned int r = p >> 8;
        packed[(size_t)lrun[bin] + r] = lpack[i];
    }
}

// ---------------- phase 4: per-bucket CSR (offsets, dinv, col) ----------------
__launch_bounds__(256)
__global__ void k_bucket_csr(const unsigned int* __restrict__ packed, const int* __restrict__ bucketBase,
                             int* __restrict__ offsets, float* __restrict__ dinv,
                             unsigned short* __restrict__ col, int N) {
    __shared__ int lcnt[256];
    __shared__ int lscan[256];
    __shared__ int lofs[256];
    int b = blockIdx.x, t = threadIdx.x;
    int s = bucketBase[b], e = bucketBase[b + 1];
    lcnt[t] = 0;
    __syncthreads();
    for (int i = s + t; i < e; i += 256) atomicAdd(&lcnt[packed[i] >> 16], 1);
    __syncthreads();
    int v = lcnt[t];
    lscan[t] = v;
    __syncthreads();
    for (int off = 1; off < 256; off <<= 1) {
        int tmp = (t >= off) ? lscan[t - off] : 0;
        __syncthreads();
        lscan[t] += tmp;
        __syncthreads();
    }
    int ex = lscan[t] - v;
    int node = b * 256 + t;
    if (node < N) {
        offsets[node] = s + ex;
        dinv[node] = rsqrtf((float)(v + 1));   // deg incl. self-loop
    }
    __syncthreads();
    lofs[t] = ex;
    lcnt[t] = 0;
    __syncthreads();
    for (int i = s + t; i < e; i += 256) {
        unsigned int p = packed[i];
        int ld = (int)(p >> 16);
        int r = atomicAdd(&lcnt[ld], 1);
        col[(size_t)s + lofs[ld] + r] = (unsigned short)(p & 0xFFFFu);
    }
}

// ---------------- GEMM1: y1b = bf16((x @ W1) * dinv[row]) ----------------
__launch_bounds__(256)
__global__ void k_gemm1(const float* __restrict__ A, const float* __restrict__ B,
                        const float* __restrict__ dinv, unsigned int* __restrict__ Yb, int M) {
    const int BM = 64, BN = 128, BK = 32, TM = 4, TN = 8;
    __shared__ float As[BK][BM + 4];   // k-major, 32x68
    __shared__ float Bs[BK][BN];       // 32x128
    int t = threadIdx.x;
    int tx = t & 15;
    int ty = t >> 4;
    int row0 = blockIdx.x * BM;
    float acc[TM][TN];
#pragma unroll
    for (int i = 0; i < TM; i++)
#pragma unroll
        for (int j = 0; j < TN; j++) acc[i][j] = 0.f;

    int am = t >> 2;
    int ak = (t & 3) * 4;
    int bk = t >> 5;
    int bn = (t & 31) * 4;

    for (int k0 = 0; k0 < F_IN; k0 += BK) {
#pragma unroll
        for (int h = 0; h < 2; h++) {
            int kk = ak + h * 16;
            int row = row0 + am;
            float4 v = (row < M) ? *(const float4*)(A + (size_t)row * F_IN + k0 + kk)
                                 : make_float4(0.f, 0.f, 0.f, 0.f);
            As[kk + 0][am] = v.x; As[kk + 1][am] = v.y; As[kk + 2][am] = v.z; As[kk + 3][am] = v.w;
        }
#pragma unroll
        for (int h = 0; h < 4; h++) {
            int kk = bk + h * 8;
            *(float4*)&Bs[kk][bn] = *(const float4*)(B + (size_t)(k0 + kk) * BN + bn);
        }
        __syncthreads();
#pragma unroll
        for (int kk = 0; kk < BK; kk++) {
            float4 a4 = *(const float4*)&As[kk][ty * TM];
            float4 b0 = *(const float4*)&Bs[kk][tx * TN];
            float4 b1 = *(const float4*)&Bs[kk][tx * TN + 4];
            float a[TM] = {a4.x, a4.y, a4.z, a4.w};
            float bv[TN] = {b0.x, b0.y, b0.z, b0.w, b1.x, b1.y, b1.z, b1.w};
#pragma unroll
            for (int i = 0; i < TM; i++)
#pragma unroll
                for (int j = 0; j < TN; j++) acc[i][j] = fmaf(a[i], bv[j], acc[i][j]);
        }
        __syncthreads();
    }
#pragma unroll
    for (int i = 0; i < TM; i++) {
        int row = row0 + ty * TM + i;
        if (row < M) {
            float d = dinv[row];
            uint4 o;
            o.x = (unsigned int)f2bf(acc[i][0] * d) | ((unsigned int)f2bf(acc[i][1] * d) << 16);
            o.y = (unsigned int)f2bf(acc[i][2] * d) | ((unsigned int)f2bf(acc[i][3] * d) << 16);
            o.z = (unsigned int)f2bf(acc[i][4] * d) | ((unsigned int)f2bf(acc[i][5] * d) << 16);
            o.w = (unsigned int)f2bf(acc[i][6] * d) | ((unsigned int)f2bf(acc[i][7] * d) << 16);
            *(uint4*)(Yb + (size_t)row * (HID / 2) + tx * (TN / 2)) = o;
        }
    }
}

// ---------------- GEMM2: y2b = bf16((hid @ W2) * dinv[row]) ----------------
__launch_bounds__(256)
__global__ void k_gemm2(const float* __restrict__ A, const float* __restrict__ B,
                        const float* __restrict__ dinv, unsigned short* __restrict__ Yb, int M) {
    const int BM = 128, BK = 32, TM = 4, TN = 5;
    __shared__ float As[BM][BK + 4];
    __shared__ float Bs[BK][C_OUT];
    int t = threadIdx.x;
    int tx = t & 7;
    int ty = t >> 3;
    int row0 = blockIdx.x * BM;
    float acc[TM][TN];
#pragma unroll
    for (int i = 0; i < TM; i++)
#pragma unroll
        for (int j = 0; j < TN; j++) acc[i][j] = 0.f;

    int am = t >> 1;

    for (int k0 = 0; k0 < HID; k0 += BK) {
#pragma unroll
        for (int h = 0; h < 4; h++) {
            int kq = (t & 1) + h * 2;
            int row = row0 + am;
            float4 v = (row < M) ? *(const float4*)(A + (size_t)row * HID + k0 + kq * 4)
                                 : make_float4(0.f, 0.f, 0.f, 0.f);
            As[am][kq * 4 + 0] = v.x; As[am][kq * 4 + 1] = v.y;
            As[am][kq * 4 + 2] = v.z; As[am][kq * 4 + 3] = v.w;
        }
        for (int l = t; l < BK * (C_OUT / 4); l += 256) {
            int kk = l / (C_OUT / 4), q = l % (C_OUT / 4);
            *(float4*)&Bs[kk][q * 4] = *(const float4*)(B + (size_t)(k0 + kk) * C_OUT + q * 4);
        }
        __syncthreads();
#pragma unroll
        for (int kk = 0; kk < BK; kk++) {
            float a[TM], bv[TN];
#pragma unroll
            for (int i = 0; i < TM; i++) a[i] = As[ty * TM + i][kk];
#pragma unroll
            for (int j = 0; j < TN; j++) bv[j] = Bs[kk][tx * TN + j];
#pragma unroll
            for (int i = 0; i < TM; i++)
#pragma unroll
                for (int j = 0; j < TN; j++) acc[i][j] = fmaf(a[i], bv[j], acc[i][j]);
        }
        __syncthreads();
    }
#pragma unroll
    for (int i = 0; i < TM; i++) {
        int row = row0 + ty * TM + i;
        if (row < M) {
            float d = dinv[row];
#pragma unroll
            for (int j = 0; j < TN; j++)
                Yb[(size_t)row * C_OUT + tx * TN + j] = f2bf(acc[i][j] * d);
        }
    }
}

// ---------------- agg1: 16 lanes/edge (uint4), 4 edges/pass ----------------
__launch_bounds__(256)
__global__ void k_agg1(const uint4* __restrict__ y1b4, const unsigned short* __restrict__ col,
                       const int* __restrict__ offsets, const float* __restrict__ dinv,
                       const float* __restrict__ b1, float* __restrict__ hid, int N) {
    int lane = threadIdx.x & 63;
    int w = threadIdx.x >> 6;
    int node = blockIdx.x * 4 + w;
    if (node >= N) return;
    int g = lane >> 4;      // edge group 0..3
    int lg = lane & 15;     // 16 lanes x uint4 = 256 B row
    int s = offsets[node], e = offsets[node + 1];

    float acc[8];
    if (g == 0) {
        uint4 sv = y1b4[(size_t)node * 16 + lg];   // self-loop
        acc[0] = bf_lo(sv.x); acc[1] = bf_hi(sv.x);
        acc[2] = bf_lo(sv.y); acc[3] = bf_hi(sv.y);
        acc[4] = bf_lo(sv.z); acc[5] = bf_hi(sv.z);
        acc[6] = bf_lo(sv.w); acc[7] = bf_hi(sv.w);
    } else {
#pragma unroll
        for (int i = 0; i < 8; i++) acc[i] = 0.f;
    }

    for (int t0 = s; t0 < e; t0 += 64) {
        int cnt = e - t0; if (cnt > 64) cnt = 64;
        int jreg = (lane < cnt) ? (int)col[t0 + lane] : 0;
        int passes = (cnt + 3) >> 2;
        for (int p = 0; p < passes; p++) {
            int idx = p * 4 + g;
            bool valid = idx < cnt;
            int j = __shfl(jreg, valid ? idx : 0);
            if (valid) {
                uint4 v = y1b4[(size_t)j * 16 + lg];
                acc[0] += bf_lo(v.x); acc[1] += bf_hi(v.x);
                acc[2] += bf_lo(v.y); acc[3] += bf_hi(v.y);
                acc[4] += bf_lo(v.z); acc[5] += bf_hi(v.z);
                acc[6] += bf_lo(v.w); acc[7] += bf_hi(v.w);
            }
        }
    }
    // reduce groups 0..3 (offsets 32, then 16)
#pragma unroll
    for (int i = 0; i < 8; i++) acc[i] += __shfl(acc[i], lane + 32);
#pragma unroll
    for (int i = 0; i < 8; i++) acc[i] += __shfl(acc[i], lane + 16);
    if (lane < 16) {
        float d = dinv[node];
        float4 bb0 = ((const float4*)b1)[lg * 2];
        float4 bb1 = ((const float4*)b1)[lg * 2 + 1];
        float4 o0, o1;
        o0.x = fmaxf(fmaf(d, acc[0], bb0.x), 0.f);
        o0.y = fmaxf(fmaf(d, acc[1], bb0.y), 0.f);
        o0.z = fmaxf(fmaf(d, acc[2], bb0.z), 0.f);
        o0.w = fmaxf(fmaf(d, acc[3], bb0.w), 0.f);
        o1.x = fmaxf(fmaf(d, acc[4], bb1.x), 0.f);
        o1.y = fmaxf(fmaf(d, acc[5], bb1.y), 0.f);
        o1.z = fmaxf(fmaf(d, acc[6], bb1.z), 0.f);
        o1.w = fmaxf(fmaf(d, acc[7], bb1.w), 0.f);
        float4* out = (float4*)(hid + (size_t)node * HID);
        out[lg * 2] = o0;
        out[lg * 2 + 1] = o1;
    }
}

// ---------------- agg2: 10 lanes/edge (uint2), 6 edges/pass + softmax ----------------
__launch_bounds__(256)
__global__ void k_agg2(const uint2* __restrict__ y2b2, const unsigned short* __restrict__ col,
                       const int* __restrict__ offsets, const float* __restrict__ dinv,
                       const float* __restrict__ b2, float* __restrict__ x2out,
                       float* __restrict__ logp, int N) {
    int lane = threadIdx.x & 63;
    int w = threadIdx.x >> 6;
    int node = blockIdx.x * 4 + w;
    if (node >= N) return;
    // groups of 10 lanes: g = lane/10 (0..5 active), lg = lane%10; lanes 60..63 idle
    int g = lane / 10;
    int lg = lane - g * 10;
    bool lact = lane < 60;
    int s = offsets[node], e = offsets[node + 1];

    float a0, a1, a2, a3;
    if (lact && g == 0) {
        uint2 sv = y2b2[(size_t)node * 10 + lg];   // self-loop
        a0 = bf_lo(sv.x); a1 = bf_hi(sv.x); a2 = bf_lo(sv.y); a3 = bf_hi(sv.y);
    } else { a0 = a1 = a2 = a3 = 0.f; }

    for (int t0 = s; t0 < e; t0 += 60) {
        int cnt = e - t0; if (cnt > 60) cnt = 60;
        int jreg = (lane < cnt) ? (int)col[t0 + lane] : 0;
        int passes = (cnt + 5) / 6;
        for (int p = 0; p < passes; p++) {
            int idx = p * 6 + g;
            bool valid = lact && idx < cnt;
            int j = __shfl(jreg, valid ? idx : 0);
            if (valid) {
                uint2 v = y2b2[(size_t)j * 10 + lg];
                a0 += bf_lo(v.x); a1 += bf_hi(v.x);
                a2 += bf_lo(v.y); a3 += bf_hi(v.y);
            }
        }
    }
    // reduce 6 groups (lanes 0,10,20,30,40,50) -> lanes 0..9
    a0 += __shfl(a0, lane + 30); a1 += __shfl(a1, lane + 30);
    a2 += __shfl(a2, lane + 30); a3 += __shfl(a3, lane + 30);
    float r0 = a0 + __shfl(a0, lane + 10) + __shfl(a0, lane + 20);
    float r1 = a1 + __shfl(a1, lane + 10) + __shfl(a1, lane + 20);
    float r2 = a2 + __shfl(a2, lane + 10) + __shfl(a2, lane + 20);
    float r3 = a3 + __shfl(a3, lane + 10) + __shfl(a3, lane + 20);

    // lanes 0..9 hold features 4*lg..4*lg+3; softmax within 16-lane group
    float x0, x1, x2v, x3;
    if (lane < 10) {
        float d = dinv[node];
        float4 bb = ((const float4*)b2)[lg];
        x0 = fmaf(d, r0, bb.x); x1 = fmaf(d, r1, bb.y);
        x2v = fmaf(d, r2, bb.z); x3 = fmaf(d, r3, bb.w);
        float4* xo = (float4*)(x2out + (size_t)node * C_OUT);
        xo[lg] = make_float4(x0, x1, x2v, x3);
    } else { x0 = x1 = x2v = x3 = -INFINITY; }

    float m = fmaxf(fmaxf(x0, x1), fmaxf(x2v, x3));
#pragma unroll
    for (int off = 1; off < 16; off <<= 1) m = fmaxf(m, __shfl_xor(m, off));
    float sum = (lane < 10) ? (expf(x0 - m) + expf(x1 - m) + expf(x2v - m) + expf(x3 - m)) : 0.f;
#pragma unroll
    for (int off = 1; off < 16; off <<= 1) sum += __shfl_xor(sum, off);
    if (lane < 10) {
        float lse = m + logf(sum);
        float4* lo = (float4*)(logp + (size_t)node * C_OUT);
        lo[lg] = make_float4(x0 - lse, x1 - lse, x2v - lse, x3 - lse);
    }
}

// ---------------- launcher ----------------
extern "C" void kernel_launch(void* const* d_in, const int* in_sizes, int n_in,
                              void* d_out, int out_size, void* d_ws, size_t ws_size,
                              hipStream_t stream) {
    const float* x  = (const float*)d_in[0];
    const int*   ei = (const int*)d_in[1];
    const float* W1 = (const float*)d_in[2];
    const float* b1 = (const float*)d_in[3];
    const float* W2 = (const float*)d_in[4];
    const float* b2 = (const float*)d_in[5];
    const int N = N_NODES;
    const int E = in_sizes[1] / 2;
    const int* src = ei;
    const int* dst = ei + E;

    float* out_hid  = (float*)d_out;                       // N*128
    float* out_x2   = out_hid + (size_t)N * HID;           // N*40
    float* out_logp = out_x2 + (size_t)N * C_OUT;          // N*40

    char* p = (char*)d_ws;
    auto alloc = [&](size_t bytes) { void* r = (void*)p; p += (bytes + 255) & ~255ull; return r; };
    int*   binCount   = (int*)alloc((size_t)BINS * 4);
    int*   bucketBase = (int*)alloc((size_t)(BINS + 1) * 4);
    int*   binCursor  = (int*)alloc((size_t)BINS * 4);
    int*   offsets    = (int*)alloc((size_t)(N + 1) * 4);
    float* dinv       = (float*)alloc((size_t)N * 4);
    unsigned int*   packed = (unsigned int*)alloc((size_t)E * 4);
    unsigned short* col    = (unsigned short*)alloc((size_t)E * 2);
    unsigned int*   y1b    = (unsigned int*)alloc((size_t)N * (HID / 2) * 4);   // bf16 x2 packed
    unsigned short* y2b    = (unsigned short*)alloc((size_t)N * C_OUT * 2);     // bf16

    hipMemsetAsync(binCount, 0, (size_t)BINS * 4, stream);
    k_hist<<<512, 256, 0, stream>>>(dst, E, binCount);
    k_scan_bins<<<1, 256, 0, stream>>>(binCount, bucketBase, binCursor, offsets, E);
    k_partition<<<(E + PCHUNK - 1) / PCHUNK, PTHREADS, 0, stream>>>(src, dst, E, binCursor, packed);
    k_bucket_csr<<<BINS, 256, 0, stream>>>(packed, bucketBase, offsets, dinv, col, N);
    k_gemm1<<<(N + 63) / 64, 256, 0, stream>>>(x, W1, dinv, y1b, N);
    k_agg1<<<(N + 3) / 4, 256, 0, stream>>>((const uint4*)y1b, col, offsets, dinv, b1, out_hid, N);
    k_gemm2<<<(N + 127) / 128, 256, 0, stream>>>(out_hid, W2, dinv, y2b, N);
    k_agg2<<<(N + 3) / 4, 256, 0, stream>>>((const uint2*)y2b, col, offsets, dinv, b2, out_x2, out_logp, N);
}

// Round 5
// 277.170 us; speedup vs baseline: 1.8515x; 1.1527x over previous
//
#include <hip/hip_runtime.h>
#include <math.h>

#define N_NODES 50000
#define F_IN 256
#define HID 128
#define C_OUT 40
#define BINS ((N_NODES + 255) / 256)   // 196 buckets of 256 nodes

typedef __attribute__((ext_vector_type(8))) short short8;
typedef __attribute__((ext_vector_type(4))) float floatx4;

__device__ __forceinline__ unsigned short f2bf(float f) {
    unsigned int u = __float_as_uint(f);
    unsigned int r = (u + 0x7FFFu + ((u >> 16) & 1u)) >> 16;
    return (unsigned short)r;
}
__device__ __forceinline__ unsigned int pack2bf(float a, float b) {
    return (unsigned int)f2bf(a) | ((unsigned int)f2bf(b) << 16);
}
__device__ __forceinline__ float bf_lo(unsigned int u) { return __uint_as_float(u << 16); }
__device__ __forceinline__ float bf_hi(unsigned int u) { return __uint_as_float(u & 0xFFFF0000u); }

// ---------------- phase 1: bucket histogram ----------------
__global__ void k_hist(const int* __restrict__ dst, int E, int* __restrict__ binCount) {
    __shared__ int h[BINS];
    for (int i = threadIdx.x; i < BINS; i += 256) h[i] = 0;
    __syncthreads();
    for (int e = blockIdx.x * 256 + threadIdx.x; e < E; e += gridDim.x * 256)
        atomicAdd(&h[dst[e] >> 8], 1);
    __syncthreads();
    for (int i = threadIdx.x; i < BINS; i += 256)
        if (h[i]) atomicAdd(&binCount[i], h[i]);
}

// ---------------- phase 2: scan buckets ----------------
__global__ void k_scan_bins(const int* __restrict__ binCount, int* __restrict__ bucketBase,
                            int* __restrict__ binCursor, int* __restrict__ offsets, int E) {
    __shared__ int sd[256];
    int t = threadIdx.x;
    int v = (t < BINS) ? binCount[t] : 0;
    sd[t] = v; __syncthreads();
    for (int off = 1; off < 256; off <<= 1) {
        int tmp = (t >= off) ? sd[t - off] : 0;
        __syncthreads();
        sd[t] += tmp;
        __syncthreads();
    }
    int ex = sd[t] - v;
    if (t < BINS) { bucketBase[t] = ex; binCursor[t] = ex; }
    if (t == 0) { bucketBase[BINS] = E; offsets[N_NODES] = E; }
}

// ---------------- phase 3: partition edges into buckets ----------------
#define PCHUNK 8192
#define PTHREADS 512
__launch_bounds__(PTHREADS)
__global__ void k_partition(const int* __restrict__ src, const int* __restrict__ dst, int E,
                            int* __restrict__ binCursor, unsigned int* __restrict__ packed) {
    __shared__ unsigned int lpack[PCHUNK];   // (local_dst<<16)|src
    __shared__ unsigned int lpos[PCHUNK];    // (rank<<8)|bin
    __shared__ int lcnt[BINS];
    __shared__ int lrun[BINS];
    int t = threadIdx.x;
    int base = blockIdx.x * PCHUNK;
    int n = E - base; if (n > PCHUNK) n = PCHUNK;
    for (int i = t; i < BINS; i += PTHREADS) lcnt[i] = 0;
    __syncthreads();
    for (int i = t; i < n; i += PTHREADS) {
        int d = dst[base + i], s = src[base + i];
        int bin = d >> 8;
        unsigned int r = (unsigned int)atomicAdd(&lcnt[bin], 1);
        lpack[i] = ((unsigned int)(d & 255) << 16) | (unsigned int)s;
        lpos[i] = (r << 8) | (unsigned int)bin;
    }
    __syncthreads();
    if (t < BINS && lcnt[t] > 0) lrun[t] = atomicAdd(&binCursor[t], lcnt[t]);
    __syncthreads();
    for (int i = t; i < n; i += PTHREADS) {
        unsigned int p = lpos[i];
        int bin = p & 255;
        unsigned int r = p >> 8;
        packed[(size_t)lrun[bin] + r] = lpack[i];
    }
}

// ---------------- phase 4: per-bucket CSR (offsets, dinv, col) ----------------
__launch_bounds__(256)
__global__ void k_bucket_csr(const unsigned int* __restrict__ packed, const int* __restrict__ bucketBase,
                             int* __restrict__ offsets, float* __restrict__ dinv,
                             unsigned short* __restrict__ col, int N) {
    __shared__ int lcnt[256];
    __shared__ int lscan[256];
    __shared__ int lofs[256];
    int b = blockIdx.x, t = threadIdx.x;
    int s = bucketBase[b], e = bucketBase[b + 1];
    lcnt[t] = 0;
    __syncthreads();
    for (int i = s + t; i < e; i += 256) atomicAdd(&lcnt[packed[i] >> 16], 1);
    __syncthreads();
    int v = lcnt[t];
    lscan[t] = v;
    __syncthreads();
    for (int off = 1; off < 256; off <<= 1) {
        int tmp = (t >= off) ? lscan[t - off] : 0;
        __syncthreads();
        lscan[t] += tmp;
        __syncthreads();
    }
    int ex = lscan[t] - v;
    int node = b * 256 + t;
    if (node < N) {
        offsets[node] = s + ex;
        dinv[node] = rsqrtf((float)(v + 1));   // deg incl. self-loop
    }
    __syncthreads();
    lofs[t] = ex;
    lcnt[t] = 0;
    __syncthreads();
    for (int i = s + t; i < e; i += 256) {
        unsigned int p = packed[i];
        int ld = (int)(p >> 16);
        int r = atomicAdd(&lcnt[ld], 1);
        col[(size_t)s + lofs[ld] + r] = (unsigned short)(p & 0xFFFFu);
    }
}

// ---------------- cast W1 -> bf16 transposed [HID][F_IN] ----------------
__global__ void k_castW1(const float* __restrict__ W1, unsigned short* __restrict__ W1bT) {
    int i = blockIdx.x * 256 + threadIdx.x;   // i = n*256 + k
    if (i < HID * F_IN) {
        int n = i >> 8, k = i & 255;
        W1bT[i] = f2bf(W1[(size_t)k * HID + n]);
    }
}

// ---------------- GEMM1 (MFMA bf16): y1b = bf16((x @ W1) * dinv[row]) ----------------
// BM=64, BN=128, BK=64. Wave w computes 64 rows x cols [w*32, w*32+32).
// y1b row layout: uint p (0..63) stores features (lo,hi) = ((p>>4)*32+(p&15), +16).
__launch_bounds__(256)
__global__ void k_gemm1(const float* __restrict__ A, const unsigned short* __restrict__ BT,
                        const float* __restrict__ dinv, unsigned int* __restrict__ Yb, int M) {
    __shared__ __align__(16) unsigned short As[64][72];    // 64 rows x 64 bf16 (+8 pad)
    __shared__ __align__(16) unsigned short Bs[128][72];   // 128 n-rows x 64 bf16 (+8 pad)
    int t = threadIdx.x;
    int w = t >> 6, lane = t & 63;
    int q = lane >> 4, m = lane & 15;
    int row0 = blockIdx.x * 64;

    floatx4 acc[4][2];
#pragma unroll
    for (int rt = 0; rt < 4; rt++)
#pragma unroll
        for (int ct = 0; ct < 2; ct++) acc[rt][ct] = (floatx4){0.f, 0.f, 0.f, 0.f};

    int ar = t >> 2;            // 0..63 A row
    int ac = (t & 3) * 16;      // 16 bf16 chunk within BK
    int brow = t >> 1;          // 0..127 B n-row
    int bh = (t & 1) * 32;      // 32 bf16 half

    for (int k0 = 0; k0 < F_IN; k0 += 64) {
        // stage A (f32 -> bf16)
        {
            int grow = row0 + ar;
            float4 v0, v1, v2, v3;
            if (grow < M) {
                const float* sp = A + (size_t)grow * F_IN + k0 + ac;
                v0 = *(const float4*)(sp);     v1 = *(const float4*)(sp + 4);
                v2 = *(const float4*)(sp + 8); v3 = *(const float4*)(sp + 12);
            } else {
                v0 = v1 = v2 = v3 = make_float4(0.f, 0.f, 0.f, 0.f);
            }
            uint4 u0, u1;
            u0.x = pack2bf(v0.x, v0.y); u0.y = pack2bf(v0.z, v0.w);
            u0.z = pack2bf(v1.x, v1.y); u0.w = pack2bf(v1.z, v1.w);
            u1.x = pack2bf(v2.x, v2.y); u1.y = pack2bf(v2.z, v2.w);
            u1.z = pack2bf(v3.x, v3.y); u1.w = pack2bf(v3.z, v3.w);
            *(uint4*)&As[ar][ac] = u0;
            *(uint4*)&As[ar][ac + 8] = u1;
        }
        // stage B (already bf16, k-contiguous)
        {
            const unsigned short* sp = BT + (size_t)brow * F_IN + k0 + bh;
            uint4 b0 = *(const uint4*)(sp);
            uint4 b1 = *(const uint4*)(sp + 8);
            uint4 b2 = *(const uint4*)(sp + 16);
            uint4 b3 = *(const uint4*)(sp + 24);
            *(uint4*)&Bs[brow][bh] = b0;
            *(uint4*)&Bs[brow][bh + 8] = b1;
            *(uint4*)&Bs[brow][bh + 16] = b2;
            *(uint4*)&Bs[brow][bh + 24] = b3;
        }
        __syncthreads();
#pragma unroll
        for (int kc = 0; kc < 64; kc += 32) {
            short8 af[4];
#pragma unroll
            for (int rt = 0; rt < 4; rt++)
                af[rt] = *(const short8*)&As[rt * 16 + m][kc + q * 8];
#pragma unroll
            for (int ct = 0; ct < 2; ct++) {
                short8 bfr = *(const short8*)&Bs[w * 32 + ct * 16 + m][kc + q * 8];
#pragma unroll
                for (int rt = 0; rt < 4; rt++)
                    acc[rt][ct] = __builtin_amdgcn_mfma_f32_16x16x32_bf16(af[rt], bfr, acc[rt][ct], 0, 0, 0);
            }
        }
        __syncthreads();
    }
    // epilogue: lane owns cols w*32+m (ct0) and w*32+16+m (ct1); pack pair -> uint p = w*16+m
#pragma unroll
    for (int rt = 0; rt < 4; rt++) {
#pragma unroll
        for (int r = 0; r < 4; r++) {
            int grow = row0 + rt * 16 + q * 4 + r;
            if (grow < M) {
                float d = dinv[grow];
                unsigned int u = pack2bf(acc[rt][0][r] * d, acc[rt][1][r] * d);
                Yb[(size_t)grow * 64 + w * 16 + m] = u;
            }
        }
    }
}

// ---------------- GEMM2: y2b = bf16((hid @ W2) * dinv[row]) ----------------
__launch_bounds__(256)
__global__ void k_gemm2(const float* __restrict__ A, const float* __restrict__ B,
                        const float* __restrict__ dinv, unsigned short* __restrict__ Yb, int M) {
    const int BM = 128, BK = 32, TM = 4, TN = 5;
    __shared__ float As[BM][BK + 4];
    __shared__ float Bs[BK][C_OUT];
    int t = threadIdx.x;
    int tx = t & 7;
    int ty = t >> 3;
    int row0 = blockIdx.x * BM;
    float acc[TM][TN];
#pragma unroll
    for (int i = 0; i < TM; i++)
#pragma unroll
        for (int j = 0; j < TN; j++) acc[i][j] = 0.f;

    int am = t >> 1;

    for (int k0 = 0; k0 < HID; k0 += BK) {
#pragma unroll
        for (int h = 0; h < 4; h++) {
            int kq = (t & 1) + h * 2;
            int row = row0 + am;
            float4 v = (row < M) ? *(const float4*)(A + (size_t)row * HID + k0 + kq * 4)
                                 : make_float4(0.f, 0.f, 0.f, 0.f);
            As[am][kq * 4 + 0] = v.x; As[am][kq * 4 + 1] = v.y;
            As[am][kq * 4 + 2] = v.z; As[am][kq * 4 + 3] = v.w;
        }
        for (int l = t; l < BK * (C_OUT / 4); l += 256) {
            int kk = l / (C_OUT / 4), qq = l % (C_OUT / 4);
            *(float4*)&Bs[kk][qq * 4] = *(const float4*)(B + (size_t)(k0 + kk) * C_OUT + qq * 4);
        }
        __syncthreads();
#pragma unroll
        for (int kk = 0; kk < BK; kk++) {
            float a[TM], bv[TN];
#pragma unroll
            for (int i = 0; i < TM; i++) a[i] = As[ty * TM + i][kk];
#pragma unroll
            for (int j = 0; j < TN; j++) bv[j] = Bs[kk][tx * TN + j];
#pragma unroll
            for (int i = 0; i < TM; i++)
#pragma unroll
                for (int j = 0; j < TN; j++) acc[i][j] = fmaf(a[i], bv[j], acc[i][j]);
        }
        __syncthreads();
    }
#pragma unroll
    for (int i = 0; i < TM; i++) {
        int row = row0 + ty * TM + i;
        if (row < M) {
            float d = dinv[row];
#pragma unroll
            for (int j = 0; j < TN; j++)
                Yb[(size_t)row * C_OUT + tx * TN + j] = f2bf(acc[i][j] * d);
        }
    }
}

// ---------------- agg1: 16 lanes/edge (uint4), 4 edges/pass ----------------
// y1b uint p -> features ((p>>4)*32+(p&15), +16); lane lg covers p = lg*4..lg*4+3.
__launch_bounds__(256)
__global__ void k_agg1(const uint4* __restrict__ y1b4, const unsigned short* __restrict__ col,
                       const int* __restrict__ offsets, const float* __restrict__ dinv,
                       const float* __restrict__ b1, float* __restrict__ hid, int N) {
    int lane = threadIdx.x & 63;
    int w = threadIdx.x >> 6;
    int node = blockIdx.x * 4 + w;
    if (node >= N) return;
    int g = lane >> 4;      // edge group 0..3
    int lg = lane & 15;     // 16 lanes x uint4 = 256 B row
    int s = offsets[node], e = offsets[node + 1];

    float accLo[4], accHi[4];
    if (g == 0) {
        uint4 sv = y1b4[(size_t)node * 16 + lg];   // self-loop
        accLo[0] = bf_lo(sv.x); accHi[0] = bf_hi(sv.x);
        accLo[1] = bf_lo(sv.y); accHi[1] = bf_hi(sv.y);
        accLo[2] = bf_lo(sv.z); accHi[2] = bf_hi(sv.z);
        accLo[3] = bf_lo(sv.w); accHi[3] = bf_hi(sv.w);
    } else {
#pragma unroll
        for (int i = 0; i < 4; i++) { accLo[i] = 0.f; accHi[i] = 0.f; }
    }

    for (int t0 = s; t0 < e; t0 += 64) {
        int cnt = e - t0; if (cnt > 64) cnt = 64;
        int jreg = (lane < cnt) ? (int)col[t0 + lane] : 0;
        int passes = (cnt + 3) >> 2;
        for (int p = 0; p < passes; p++) {
            int idx = p * 4 + g;
            bool valid = idx < cnt;
            int j = __shfl(jreg, valid ? idx : 0);
            if (valid) {
                uint4 v = y1b4[(size_t)j * 16 + lg];
                accLo[0] += bf_lo(v.x); accHi[0] += bf_hi(v.x);
                accLo[1] += bf_lo(v.y); accHi[1] += bf_hi(v.y);
                accLo[2] += bf_lo(v.z); accHi[2] += bf_hi(v.z);
                accLo[3] += bf_lo(v.w); accHi[3] += bf_hi(v.w);
            }
        }
    }
#pragma unroll
    for (int i = 0; i < 4; i++) {
        accLo[i] += __shfl(accLo[i], lane + 32);
        accHi[i] += __shfl(accHi[i], lane + 32);
    }
#pragma unroll
    for (int i = 0; i < 4; i++) {
        accLo[i] += __shfl(accLo[i], lane + 16);
        accHi[i] += __shfl(accHi[i], lane + 16);
    }
    if (lane < 16) {
        float d = dinv[node];
        int base = (lg >> 2) * 32 + (lg & 3) * 4;   // feature base for p=lg*4..lg*4+3
        float4 bbL = *(const float4*)(b1 + base);
        float4 bbH = *(const float4*)(b1 + base + 16);
        float4 oL, oH;
        oL.x = fmaxf(fmaf(d, accLo[0], bbL.x), 0.f);
        oL.y = fmaxf(fmaf(d, accLo[1], bbL.y), 0.f);
        oL.z = fmaxf(fmaf(d, accLo[2], bbL.z), 0.f);
        oL.w = fmaxf(fmaf(d, accLo[3], bbL.w), 0.f);
        oH.x = fmaxf(fmaf(d, accHi[0], bbH.x), 0.f);
        oH.y = fmaxf(fmaf(d, accHi[1], bbH.y), 0.f);
        oH.z = fmaxf(fmaf(d, accHi[2], bbH.z), 0.f);
        oH.w = fmaxf(fmaf(d, accHi[3], bbH.w), 0.f);
        *(float4*)(hid + (size_t)node * HID + base) = oL;
        *(float4*)(hid + (size_t)node * HID + base + 16) = oH;
    }
}

// ---------------- agg2: 10 lanes/edge (uint2), 6 edges/pass + softmax ----------------
__launch_bounds__(256)
__global__ void k_agg2(const uint2* __restrict__ y2b2, const unsigned short* __restrict__ col,
                       const int* __restrict__ offsets, const float* __restrict__ dinv,
                       const float* __restrict__ b2, float* __restrict__ x2out,
                       float* __restrict__ logp, int N) {
    int lane = threadIdx.x & 63;
    int w = threadIdx.x >> 6;
    int node = blockIdx.x * 4 + w;
    if (node >= N) return;
    int g = lane / 10;
    int lg = lane - g * 10;
    bool lact = lane < 60;
    int s = offsets[node], e = offsets[node + 1];

    float a0, a1, a2, a3;
    if (lact && g == 0) {
        uint2 sv = y2b2[(size_t)node * 10 + lg];   // self-loop
        a0 = bf_lo(sv.x); a1 = bf_hi(sv.x); a2 = bf_lo(sv.y); a3 = bf_hi(sv.y);
    } else { a0 = a1 = a2 = a3 = 0.f; }

    for (int t0 = s; t0 < e; t0 += 60) {
        int cnt = e - t0; if (cnt > 60) cnt = 60;
        int jreg = (lane < cnt) ? (int)col[t0 + lane] : 0;
        int passes = (cnt + 5) / 6;
        for (int p = 0; p < passes; p++) {
            int idx = p * 6 + g;
            bool valid = lact && idx < cnt;
            int j = __shfl(jreg, valid ? idx : 0);
            if (valid) {
                uint2 v = y2b2[(size_t)j * 10 + lg];
                a0 += bf_lo(v.x); a1 += bf_hi(v.x);
                a2 += bf_lo(v.y); a3 += bf_hi(v.y);
            }
        }
    }
    a0 += __shfl(a0, lane + 30); a1 += __shfl(a1, lane + 30);
    a2 += __shfl(a2, lane + 30); a3 += __shfl(a3, lane + 30);
    float r0 = a0 + __shfl(a0, lane + 10) + __shfl(a0, lane + 20);
    float r1 = a1 + __shfl(a1, lane + 10) + __shfl(a1, lane + 20);
    float r2 = a2 + __shfl(a2, lane + 10) + __shfl(a2, lane + 20);
    float r3 = a3 + __shfl(a3, lane + 10) + __shfl(a3, lane + 20);

    float x0, x1, x2v, x3;
    if (lane < 10) {
        float d = dinv[node];
        float4 bb = ((const float4*)b2)[lg];
        x0 = fmaf(d, r0, bb.x); x1 = fmaf(d, r1, bb.y);
        x2v = fmaf(d, r2, bb.z); x3 = fmaf(d, r3, bb.w);
        float4* xo = (float4*)(x2out + (size_t)node * C_OUT);
        xo[lg] = make_float4(x0, x1, x2v, x3);
    } else { x0 = x1 = x2v = x3 = -INFINITY; }

    float m = fmaxf(fmaxf(x0, x1), fmaxf(x2v, x3));
#pragma unroll
    for (int off = 1; off < 16; off <<= 1) m = fmaxf(m, __shfl_xor(m, off));
    float sum = (lane < 10) ? (expf(x0 - m) + expf(x1 - m) + expf(x2v - m) + expf(x3 - m)) : 0.f;
#pragma unroll
    for (int off = 1; off < 16; off <<= 1) sum += __shfl_xor(sum, off);
    if (lane < 10) {
        float lse = m + logf(sum);
        float4* lo = (float4*)(logp + (size_t)node * C_OUT);
        lo[lg] = make_float4(x0 - lse, x1 - lse, x2v - lse, x3 - lse);
    }
}

// ---------------- launcher ----------------
extern "C" void kernel_launch(void* const* d_in, const int* in_sizes, int n_in,
                              void* d_out, int out_size, void* d_ws, size_t ws_size,
                              hipStream_t stream) {
    const float* x  = (const float*)d_in[0];
    const int*   ei = (const int*)d_in[1];
    const float* W1 = (const float*)d_in[2];
    const float* b1 = (const float*)d_in[3];
    const float* W2 = (const float*)d_in[4];
    const float* b2 = (const float*)d_in[5];
    const int N = N_NODES;
    const int E = in_sizes[1] / 2;
    const int* src = ei;
    const int* dst = ei + E;

    float* out_hid  = (float*)d_out;                       // N*128
    float* out_x2   = out_hid + (size_t)N * HID;           // N*40
    float* out_logp = out_x2 + (size_t)N * C_OUT;          // N*40

    char* p = (char*)d_ws;
    auto alloc = [&](size_t bytes) { void* r = (void*)p; p += (bytes + 255) & ~255ull; return r; };
    int*   binCount   = (int*)alloc((size_t)BINS * 4);
    int*   bucketBase = (int*)alloc((size_t)(BINS + 1) * 4);
    int*   binCursor  = (int*)alloc((size_t)BINS * 4);
    int*   offsets    = (int*)alloc((size_t)(N + 1) * 4);
    float* dinv       = (float*)alloc((size_t)N * 4);
    unsigned int*   packed = (unsigned int*)alloc((size_t)E * 4);
    unsigned short* col    = (unsigned short*)alloc((size_t)E * 2);
    unsigned int*   y1b    = (unsigned int*)alloc((size_t)N * (HID / 2) * 4);   // bf16 x2 packed
    unsigned short* y2b    = (unsigned short*)alloc((size_t)N * C_OUT * 2);     // bf16
    unsigned short* W1bT   = (unsigned short*)alloc((size_t)HID * F_IN * 2);    // bf16 [N][K]

    hipMemsetAsync(binCount, 0, (size_t)BINS * 4, stream);
    k_hist<<<512, 256, 0, stream>>>(dst, E, binCount);
    k_scan_bins<<<1, 256, 0, stream>>>(binCount, bucketBase, binCursor, offsets, E);
    k_partition<<<(E + PCHUNK - 1) / PCHUNK, PTHREADS, 0, stream>>>(src, dst, E, binCursor, packed);
    k_bucket_csr<<<BINS, 256, 0, stream>>>(packed, bucketBase, offsets, dinv, col, N);
    k_castW1<<<(HID * F_IN + 255) / 256, 256, 0, stream>>>(W1, W1bT);
    k_gemm1<<<(N + 63) / 64, 256, 0, stream>>>(x, W1bT, dinv, y1b, N);
    k_agg1<<<(N + 3) / 4, 256, 0, stream>>>((const uint4*)y1b, col, offsets, dinv, b1, out_hid, N);
    k_gemm2<<<(N + 127) / 128, 256, 0, stream>>>(out_hid, W2, dinv, y2b, N);
    k_agg2<<<(N + 3) / 4, 256, 0, stream>>>((const uint2*)y2b, col, offsets, dinv, b2, out_x2, out_logp, N);
}

// Round 6
// 269.255 us; speedup vs baseline: 1.9060x; 1.0294x over previous
//
#include <hip/hip_runtime.h>
#include <math.h>

#define N_NODES 50000
#define F_IN 256
#define HID 128
#define C_OUT 40
#define BINS ((N_NODES + 255) / 256)   // 196 buckets of 256 nodes

typedef __attribute__((ext_vector_type(8))) short short8;
typedef __attribute__((ext_vector_type(4))) float floatx4;
typedef __attribute__((ext_vector_type(2))) float floatx2;

__device__ __forceinline__ unsigned short f2bf(float f) {
    unsigned int u = __float_as_uint(f);
    unsigned int r = (u + 0x7FFFu + ((u >> 16) & 1u)) >> 16;
    return (unsigned short)r;
}
__device__ __forceinline__ unsigned int pack2bf(float a, float b) {
    return (unsigned int)f2bf(a) | ((unsigned int)f2bf(b) << 16);
}
__device__ __forceinline__ float bf_lo(unsigned int u) { return __uint_as_float(u << 16); }
__device__ __forceinline__ float bf_hi(unsigned int u) { return __uint_as_float(u & 0xFFFF0000u); }

// ---------------- phase 1: bucket histogram ----------------
__global__ void k_hist(const int* __restrict__ dst, int E, int* __restrict__ binCount) {
    __shared__ int h[BINS];
    for (int i = threadIdx.x; i < BINS; i += 256) h[i] = 0;
    __syncthreads();
    for (int e = blockIdx.x * 256 + threadIdx.x; e < E; e += gridDim.x * 256)
        atomicAdd(&h[dst[e] >> 8], 1);
    __syncthreads();
    for (int i = threadIdx.x; i < BINS; i += 256)
        if (h[i]) atomicAdd(&binCount[i], h[i]);
}

// ---------------- phase 2: scan buckets ----------------
__global__ void k_scan_bins(const int* __restrict__ binCount, int* __restrict__ bucketBase,
                            int* __restrict__ binCursor, int* __restrict__ offsets, int E) {
    __shared__ int sd[256];
    int t = threadIdx.x;
    int v = (t < BINS) ? binCount[t] : 0;
    sd[t] = v; __syncthreads();
    for (int off = 1; off < 256; off <<= 1) {
        int tmp = (t >= off) ? sd[t - off] : 0;
        __syncthreads();
        sd[t] += tmp;
        __syncthreads();
    }
    int ex = sd[t] - v;
    if (t < BINS) { bucketBase[t] = ex; binCursor[t] = ex; }
    if (t == 0) { bucketBase[BINS] = E; offsets[N_NODES] = E; }
}

// ---------------- phase 3: partition edges into buckets ----------------
#define PCHUNK 4096
#define PTHREADS 256
__launch_bounds__(PTHREADS)
__global__ void k_partition(const int* __restrict__ src, const int* __restrict__ dst, int E,
                            int* __restrict__ binCursor, unsigned int* __restrict__ packed) {
    __shared__ unsigned int lpack[PCHUNK];   // (local_dst<<16)|src
    __shared__ unsigned int lpos[PCHUNK];    // (rank<<8)|bin
    __shared__ int lcnt[BINS];
    __shared__ int lrun[BINS];
    int t = threadIdx.x;
    int base = blockIdx.x * PCHUNK;
    int n = E - base; if (n > PCHUNK) n = PCHUNK;
    for (int i = t; i < BINS; i += PTHREADS) lcnt[i] = 0;
    __syncthreads();
    for (int i = t; i < n; i += PTHREADS) {
        int d = dst[base + i], s = src[base + i];
        int bin = d >> 8;
        unsigned int r = (unsigned int)atomicAdd(&lcnt[bin], 1);
        lpack[i] = ((unsigned int)(d & 255) << 16) | (unsigned int)s;
        lpos[i] = (r << 8) | (unsigned int)bin;
    }
    __syncthreads();
    if (t < BINS && lcnt[t] > 0) lrun[t] = atomicAdd(&binCursor[t], lcnt[t]);
    __syncthreads();
    for (int i = t; i < n; i += PTHREADS) {
        unsigned int p = lpos[i];
        int bin = p & 255;
        unsigned int r = p >> 8;
        packed[(size_t)lrun[bin] + r] = lpack[i];
    }
}

// ---------------- phase 4: per-bucket CSR (offsets, dinv, col) ----------------
__launch_bounds__(256)
__global__ void k_bucket_csr(const unsigned int* __restrict__ packed, const int* __restrict__ bucketBase,
                             int* __restrict__ offsets, float* __restrict__ dinv,
                             unsigned short* __restrict__ col, int N) {
    __shared__ int lcnt[256];
    __shared__ int lscan[256];
    __shared__ int lofs[256];
    int b = blockIdx.x, t = threadIdx.x;
    int s = bucketBase[b], e = bucketBase[b + 1];
    lcnt[t] = 0;
    __syncthreads();
    for (int i = s + t; i < e; i += 256) atomicAdd(&lcnt[packed[i] >> 16], 1);
    __syncthreads();
    int v = lcnt[t];
    lscan[t] = v;
    __syncthreads();
    for (int off = 1; off < 256; off <<= 1) {
        int tmp = (t >= off) ? lscan[t - off] : 0;
        __syncthreads();
        lscan[t] += tmp;
        __syncthreads();
    }
    int ex = lscan[t] - v;
    int node = b * 256 + t;
    if (node < N) {
        offsets[node] = s + ex;
        dinv[node] = rsqrtf((float)(v + 1));   // deg incl. self-loop
    }
    __syncthreads();
    lofs[t] = ex;
    lcnt[t] = 0;
    __syncthreads();
    for (int i = s + t; i < e; i += 256) {
        unsigned int p = packed[i];
        int ld = (int)(p >> 16);
        int r = atomicAdd(&lcnt[ld], 1);
        col[(size_t)s + lofs[ld] + r] = (unsigned short)(p & 0xFFFFu);
    }
}

// ---------------- cast W1 -> bf16 transposed [HID][F_IN] ----------------
__global__ void k_castW1(const float* __restrict__ W1, unsigned short* __restrict__ W1bT) {
    int i = blockIdx.x * 256 + threadIdx.x;   // i = n*256 + k
    if (i < HID * F_IN) {
        int n = i >> 8, k = i & 255;
        W1bT[i] = f2bf(W1[(size_t)k * HID + n]);
    }
}

// ---------------- GEMM1 (MFMA bf16): y1f = fp8((x @ W1) * dinv[row]) ----------------
// BM=64, BN=128, BK=64. Wave w computes 64 rows x cols [w*32, w*32+32).
// y1f row layout: ushort p (0..63) stores fp8 pair (lo,hi) = features ((p>>4)*32+(p&15), +16).
__launch_bounds__(256)
__global__ void k_gemm1(const float* __restrict__ A, const unsigned short* __restrict__ BT,
                        const float* __restrict__ dinv, unsigned short* __restrict__ Yf, int M) {
    __shared__ __align__(16) unsigned short As[64][72];    // 64 rows x 64 bf16 (+8 pad)
    __shared__ __align__(16) unsigned short Bs[128][72];   // 128 n-rows x 64 bf16 (+8 pad)
    int t = threadIdx.x;
    int w = t >> 6, lane = t & 63;
    int q = lane >> 4, m = lane & 15;
    int row0 = blockIdx.x * 64;

    floatx4 acc[4][2];
#pragma unroll
    for (int rt = 0; rt < 4; rt++)
#pragma unroll
        for (int ct = 0; ct < 2; ct++) acc[rt][ct] = (floatx4){0.f, 0.f, 0.f, 0.f};

    int ar = t >> 2;            // 0..63 A row
    int ac = (t & 3) * 16;      // 16 bf16 chunk within BK
    int brow = t >> 1;          // 0..127 B n-row
    int bh = (t & 1) * 32;      // 32 bf16 half

    for (int k0 = 0; k0 < F_IN; k0 += 64) {
        // stage A (f32 -> bf16)
        {
            int grow = row0 + ar;
            float4 v0, v1, v2, v3;
            if (grow < M) {
                const float* sp = A + (size_t)grow * F_IN + k0 + ac;
                v0 = *(const float4*)(sp);     v1 = *(const float4*)(sp + 4);
                v2 = *(const float4*)(sp + 8); v3 = *(const float4*)(sp + 12);
            } else {
                v0 = v1 = v2 = v3 = make_float4(0.f, 0.f, 0.f, 0.f);
            }
            uint4 u0, u1;
            u0.x = pack2bf(v0.x, v0.y); u0.y = pack2bf(v0.z, v0.w);
            u0.z = pack2bf(v1.x, v1.y); u0.w = pack2bf(v1.z, v1.w);
            u1.x = pack2bf(v2.x, v2.y); u1.y = pack2bf(v2.z, v2.w);
            u1.z = pack2bf(v3.x, v3.y); u1.w = pack2bf(v3.z, v3.w);
            *(uint4*)&As[ar][ac] = u0;
            *(uint4*)&As[ar][ac + 8] = u1;
        }
        // stage B (already bf16, k-contiguous)
        {
            const unsigned short* sp = BT + (size_t)brow * F_IN + k0 + bh;
            uint4 b0 = *(const uint4*)(sp);
            uint4 b1 = *(const uint4*)(sp + 8);
            uint4 b2 = *(const uint4*)(sp + 16);
            uint4 b3 = *(const uint4*)(sp + 24);
            *(uint4*)&Bs[brow][bh] = b0;
            *(uint4*)&Bs[brow][bh + 8] = b1;
            *(uint4*)&Bs[brow][bh + 16] = b2;
            *(uint4*)&Bs[brow][bh + 24] = b3;
        }
        __syncthreads();
#pragma unroll
        for (int kc = 0; kc < 64; kc += 32) {
            short8 af[4];
#pragma unroll
            for (int rt = 0; rt < 4; rt++)
                af[rt] = *(const short8*)&As[rt * 16 + m][kc + q * 8];
#pragma unroll
            for (int ct = 0; ct < 2; ct++) {
                short8 bfr = *(const short8*)&Bs[w * 32 + ct * 16 + m][kc + q * 8];
#pragma unroll
                for (int rt = 0; rt < 4; rt++)
                    acc[rt][ct] = __builtin_amdgcn_mfma_f32_16x16x32_bf16(af[rt], bfr, acc[rt][ct], 0, 0, 0);
            }
        }
        __syncthreads();
    }
    // epilogue: lane owns cols w*32+m (ct0) and w*32+16+m (ct1) = the fp8 pair for p = w*16+m
#pragma unroll
    for (int rt = 0; rt < 4; rt++) {
#pragma unroll
        for (int r = 0; r < 4; r++) {
            int grow = row0 + rt * 16 + q * 4 + r;
            if (grow < M) {
                float d = dinv[grow];
                int pk = __builtin_amdgcn_cvt_pk_fp8_f32(acc[rt][0][r] * d, acc[rt][1][r] * d, 0, false);
                Yf[(size_t)grow * 64 + w * 16 + m] = (unsigned short)pk;
            }
        }
    }
}

// ---------------- GEMM2: y2b = bf16((hid @ W2) * dinv[row]) ----------------
__launch_bounds__(256)
__global__ void k_gemm2(const float* __restrict__ A, const float* __restrict__ B,
                        const float* __restrict__ dinv, unsigned short* __restrict__ Yb, int M) {
    const int BM = 128, BK = 32, TM = 4, TN = 5;
    __shared__ float As[BM][BK + 4];
    __shared__ float Bs[BK][C_OUT];
    int t = threadIdx.x;
    int tx = t & 7;
    int ty = t >> 3;
    int row0 = blockIdx.x * BM;
    float acc[TM][TN];
#pragma unroll
    for (int i = 0; i < TM; i++)
#pragma unroll
        for (int j = 0; j < TN; j++) acc[i][j] = 0.f;

    int am = t >> 1;

    for (int k0 = 0; k0 < HID; k0 += BK) {
#pragma unroll
        for (int h = 0; h < 4; h++) {
            int kq = (t & 1) + h * 2;
            int row = row0 + am;
            float4 v = (row < M) ? *(const float4*)(A + (size_t)row * HID + k0 + kq * 4)
                                 : make_float4(0.f, 0.f, 0.f, 0.f);
            As[am][kq * 4 + 0] = v.x; As[am][kq * 4 + 1] = v.y;
            As[am][kq * 4 + 2] = v.z; As[am][kq * 4 + 3] = v.w;
        }
        for (int l = t; l < BK * (C_OUT / 4); l += 256) {
            int kk = l / (C_OUT / 4), qq = l % (C_OUT / 4);
            *(float4*)&Bs[kk][qq * 4] = *(const float4*)(B + (size_t)(k0 + kk) * C_OUT + qq * 4);
        }
        __syncthreads();
#pragma unroll
        for (int kk = 0; kk < BK; kk++) {
            float a[TM], bv[TN];
#pragma unroll
            for (int i = 0; i < TM; i++) a[i] = As[ty * TM + i][kk];
#pragma unroll
            for (int j = 0; j < TN; j++) bv[j] = Bs[kk][tx * TN + j];
#pragma unroll
            for (int i = 0; i < TM; i++)
#pragma unroll
                for (int j = 0; j < TN; j++) acc[i][j] = fmaf(a[i], bv[j], acc[i][j]);
        }
        __syncthreads();
    }
#pragma unroll
    for (int i = 0; i < TM; i++) {
        int row = row0 + ty * TM + i;
        if (row < M) {
            float d = dinv[row];
#pragma unroll
            for (int j = 0; j < TN; j++)
                Yb[(size_t)row * C_OUT + tx * TN + j] = f2bf(acc[i][j] * d);
        }
    }
}

// ---------------- agg1: 16 lanes/edge (uint2 fp8), 4 edges/pass ----------------
// y1f ushort p -> features ((p>>4)*32+(p&15), +16); lane lg covers p = lg*4..lg*4+3.
__launch_bounds__(256)
__global__ void k_agg1(const uint2* __restrict__ y1f2, const unsigned short* __restrict__ col,
                       const int* __restrict__ offsets, const float* __restrict__ dinv,
                       const float* __restrict__ b1, float* __restrict__ hid, int N) {
    int lane = threadIdx.x & 63;
    int w = threadIdx.x >> 6;
    int node = blockIdx.x * 4 + w;
    if (node >= N) return;
    int g = lane >> 4;      // edge group 0..3
    int lg = lane & 15;     // 16 lanes x uint2 = 128 B row
    int s = offsets[node], e = offsets[node + 1];

    float accLo[4], accHi[4];
    if (g == 0) {
        uint2 sv = y1f2[(size_t)node * 16 + lg];   // self-loop
        floatx2 d0 = __builtin_amdgcn_cvt_pk_f32_fp8(sv.x, false);
        floatx2 d1 = __builtin_amdgcn_cvt_pk_f32_fp8(sv.x, true);
        floatx2 d2 = __builtin_amdgcn_cvt_pk_f32_fp8(sv.y, false);
        floatx2 d3 = __builtin_amdgcn_cvt_pk_f32_fp8(sv.y, true);
        accLo[0] = d0[0]; accHi[0] = d0[1];
        accLo[1] = d1[0]; accHi[1] = d1[1];
        accLo[2] = d2[0]; accHi[2] = d2[1];
        accLo[3] = d3[0]; accHi[3] = d3[1];
    } else {
#pragma unroll
        for (int i = 0; i < 4; i++) { accLo[i] = 0.f; accHi[i] = 0.f; }
    }

    for (int t0 = s; t0 < e; t0 += 64) {
        int cnt = e - t0; if (cnt > 64) cnt = 64;
        int jreg = (lane < cnt) ? (int)col[t0 + lane] : 0;
        int passes = (cnt + 3) >> 2;
        for (int p = 0; p < passes; p++) {
            int idx = p * 4 + g;
            bool valid = idx < cnt;
            int j = __shfl(jreg, valid ? idx : 0);
            if (valid) {
                uint2 v = y1f2[(size_t)j * 16 + lg];
                floatx2 d0 = __builtin_amdgcn_cvt_pk_f32_fp8(v.x, false);
                floatx2 d1 = __builtin_amdgcn_cvt_pk_f32_fp8(v.x, true);
                floatx2 d2 = __builtin_amdgcn_cvt_pk_f32_fp8(v.y, false);
                floatx2 d3 = __builtin_amdgcn_cvt_pk_f32_fp8(v.y, true);
                accLo[0] += d0[0]; accHi[0] += d0[1];
                accLo[1] += d1[0]; accHi[1] += d1[1];
                accLo[2] += d2[0]; accHi[2] += d2[1];
                accLo[3] += d3[0]; accHi[3] += d3[1];
            }
        }
    }
#pragma unroll
    for (int i = 0; i < 4; i++) {
        accLo[i] += __shfl(accLo[i], lane + 32);
        accHi[i] += __shfl(accHi[i], lane + 32);
    }
#pragma unroll
    for (int i = 0; i < 4; i++) {
        accLo[i] += __shfl(accLo[i], lane + 16);
        accHi[i] += __shfl(accHi[i], lane + 16);
    }
    if (lane < 16) {
        float d = dinv[node];
        int base = (lg >> 2) * 32 + (lg & 3) * 4;   // feature base for p=lg*4..lg*4+3
        float4 bbL = *(const float4*)(b1 + base);
        float4 bbH = *(const float4*)(b1 + base + 16);
        float4 oL, oH;
        oL.x = fmaxf(fmaf(d, accLo[0], bbL.x), 0.f);
        oL.y = fmaxf(fmaf(d, accLo[1], bbL.y), 0.f);
        oL.z = fmaxf(fmaf(d, accLo[2], bbL.z), 0.f);
        oL.w = fmaxf(fmaf(d, accLo[3], bbL.w), 0.f);
        oH.x = fmaxf(fmaf(d, accHi[0], bbH.x), 0.f);
        oH.y = fmaxf(fmaf(d, accHi[1], bbH.y), 0.f);
        oH.z = fmaxf(fmaf(d, accHi[2], bbH.z), 0.f);
        oH.w = fmaxf(fmaf(d, accHi[3], bbH.w), 0.f);
        *(float4*)(hid + (size_t)node * HID + base) = oL;
        *(float4*)(hid + (size_t)node * HID + base + 16) = oH;
    }
}

// ---------------- agg2: 10 lanes/edge (uint2), 6 edges/pass + softmax ----------------
__launch_bounds__(256)
__global__ void k_agg2(const uint2* __restrict__ y2b2, const unsigned short* __restrict__ col,
                       const int* __restrict__ offsets, const float* __restrict__ dinv,
                       const float* __restrict__ b2, float* __restrict__ x2out,
                       float* __restrict__ logp, int N) {
    int lane = threadIdx.x & 63;
    int w = threadIdx.x >> 6;
    int node = blockIdx.x * 4 + w;
    if (node >= N) return;
    int g = lane / 10;
    int lg = lane - g * 10;
    bool lact = lane < 60;
    int s = offsets[node], e = offsets[node + 1];

    float a0, a1, a2, a3;
    if (lact && g == 0) {
        uint2 sv = y2b2[(size_t)node * 10 + lg];   // self-loop
        a0 = bf_lo(sv.x); a1 = bf_hi(sv.x); a2 = bf_lo(sv.y); a3 = bf_hi(sv.y);
    } else { a0 = a1 = a2 = a3 = 0.f; }

    for (int t0 = s; t0 < e; t0 += 60) {
        int cnt = e - t0; if (cnt > 60) cnt = 60;
        int jreg = (lane < cnt) ? (int)col[t0 + lane] : 0;
        int passes = (cnt + 5) / 6;
        for (int p = 0; p < passes; p++) {
            int idx = p * 6 + g;
            bool valid = lact && idx < cnt;
            int j = __shfl(jreg, valid ? idx : 0);
            if (valid) {
                uint2 v = y2b2[(size_t)j * 10 + lg];
                a0 += bf_lo(v.x); a1 += bf_hi(v.x);
                a2 += bf_lo(v.y); a3 += bf_hi(v.y);
            }
        }
    }
    a0 += __shfl(a0, lane + 30); a1 += __shfl(a1, lane + 30);
    a2 += __shfl(a2, lane + 30); a3 += __shfl(a3, lane + 30);
    float r0 = a0 + __shfl(a0, lane + 10) + __shfl(a0, lane + 20);
    float r1 = a1 + __shfl(a1, lane + 10) + __shfl(a1, lane + 20);
    float r2 = a2 + __shfl(a2, lane + 10) + __shfl(a2, lane + 20);
    float r3 = a3 + __shfl(a3, lane + 10) + __shfl(a3, lane + 20);

    float x0, x1, x2v, x3;
    if (lane < 10) {
        float d = dinv[node];
        float4 bb = ((const float4*)b2)[lg];
        x0 = fmaf(d, r0, bb.x); x1 = fmaf(d, r1, bb.y);
        x2v = fmaf(d, r2, bb.z); x3 = fmaf(d, r3, bb.w);
        float4* xo = (float4*)(x2out + (size_t)node * C_OUT);
        xo[lg] = make_float4(x0, x1, x2v, x3);
    } else { x0 = x1 = x2v = x3 = -INFINITY; }

    float m = fmaxf(fmaxf(x0, x1), fmaxf(x2v, x3));
#pragma unroll
    for (int off = 1; off < 16; off <<= 1) m = fmaxf(m, __shfl_xor(m, off));
    float sum = (lane < 10) ? (expf(x0 - m) + expf(x1 - m) + expf(x2v - m) + expf(x3 - m)) : 0.f;
#pragma unroll
    for (int off = 1; off < 16; off <<= 1) sum += __shfl_xor(sum, off);
    if (lane < 10) {
        float lse = m + logf(sum);
        float4* lo = (float4*)(logp + (size_t)node * C_OUT);
        lo[lg] = make_float4(x0 - lse, x1 - lse, x2v - lse, x3 - lse);
    }
}

// ---------------- launcher ----------------
extern "C" void kernel_launch(void* const* d_in, const int* in_sizes, int n_in,
                              void* d_out, int out_size, void* d_ws, size_t ws_size,
                              hipStream_t stream) {
    const float* x  = (const float*)d_in[0];
    const int*   ei = (const int*)d_in[1];
    const float* W1 = (const float*)d_in[2];
    const float* b1 = (const float*)d_in[3];
    const float* W2 = (const float*)d_in[4];
    const float* b2 = (const float*)d_in[5];
    const int N = N_NODES;
    const int E = in_sizes[1] / 2;
    const int* src = ei;
    const int* dst = ei + E;

    float* out_hid  = (float*)d_out;                       // N*128
    float* out_x2   = out_hid + (size_t)N * HID;           // N*40
    float* out_logp = out_x2 + (size_t)N * C_OUT;          // N*40

    char* p = (char*)d_ws;
    auto alloc = [&](size_t bytes) { void* r = (void*)p; p += (bytes + 255) & ~255ull; return r; };
    int*   binCount   = (int*)alloc((size_t)BINS * 4);
    int*   bucketBase = (int*)alloc((size_t)(BINS + 1) * 4);
    int*   binCursor  = (int*)alloc((size_t)BINS * 4);
    int*   offsets    = (int*)alloc((size_t)(N + 1) * 4);
    float* dinv       = (float*)alloc((size_t)N * 4);
    unsigned int*   packed = (unsigned int*)alloc((size_t)E * 4);
    unsigned short* col    = (unsigned short*)alloc((size_t)E * 2);
    unsigned short* y1f    = (unsigned short*)alloc((size_t)N * 64 * 2);        // fp8 pairs
    unsigned short* y2b    = (unsigned short*)alloc((size_t)N * C_OUT * 2);     // bf16
    unsigned short* W1bT   = (unsigned short*)alloc((size_t)HID * F_IN * 2);    // bf16 [N][K]

    hipMemsetAsync(binCount, 0, (size_t)BINS * 4, stream);
    k_hist<<<512, 256, 0, stream>>>(dst, E, binCount);
    k_scan_bins<<<1, 256, 0, stream>>>(binCount, bucketBase, binCursor, offsets, E);
    k_partition<<<(E + PCHUNK - 1) / PCHUNK, PTHREADS, 0, stream>>>(src, dst, E, binCursor, packed);
    k_bucket_csr<<<BINS, 256, 0, stream>>>(packed, bucketBase, offsets, dinv, col, N);
    k_castW1<<<(HID * F_IN + 255) / 256, 256, 0, stream>>>(W1, W1bT);
    k_gemm1<<<(N + 63) / 64, 256, 0, stream>>>(x, W1bT, dinv, y1f, N);
    k_agg1<<<(N + 3) / 4, 256, 0, stream>>>((const uint2*)y1f, col, offsets, dinv, b1, out_hid, N);
    k_gemm2<<<(N + 127) / 128, 256, 0, stream>>>(out_hid, W2, dinv, y2b, N);
    k_agg2<<<(N + 3) / 4, 256, 0, stream>>>((const uint2*)y2b, col, offsets, dinv, b2, out_x2, out_logp, N);
}